// Round 1
// baseline (1872.913 us; speedup 1.0000x reference)
//
#include <hip/hip_runtime.h>

#define N_NODES 50000
#define F_IN 256
#define HID 128
#define CLS 32
#define N_EDGE 800000

// ---------------- degree / normalization ----------------

__global__ __launch_bounds__(256) void k_deg_init(float* __restrict__ deg) {
    int i = blockIdx.x * 256 + threadIdx.x;
    if (i < N_NODES) deg[i] = 1.0f;   // self-loop
}

__global__ __launch_bounds__(256) void k_deg_scatter(const int* __restrict__ dst,
                                                     float* __restrict__ deg) {
    int e = blockIdx.x * 256 + threadIdx.x;
    if (e < N_EDGE) atomicAdd(&deg[dst[e]], 1.0f);
}

__global__ __launch_bounds__(256) void k_rsqrt(float* __restrict__ deg) {
    int i = blockIdx.x * 256 + threadIdx.x;
    if (i < N_NODES) deg[i] = rsqrtf(deg[i]);
}

// ---------------- GEMM1: h1[N][128] = x[N][256] @ W1[256][128] ----------------
// 256 threads: 32 col-quads (j) x 8 row-groups; each thread does 4 rows x 4 cols.
// Block covers 32 rows x 128 cols.

__global__ __launch_bounds__(256) void k_gemm1(const float* __restrict__ x,
                                               const float* __restrict__ W,
                                               float* __restrict__ h) {
    const int jq = threadIdx.x & 31;
    const int ig = threadIdx.x >> 5;
    const int j = jq * 4;
    const int row0 = blockIdx.x * 32 + ig * 4;

    int r[4];
#pragma unroll
    for (int t = 0; t < 4; ++t) r[t] = min(row0 + t, N_NODES - 1);

    const float* x0 = x + (size_t)r[0] * F_IN;
    const float* x1 = x + (size_t)r[1] * F_IN;
    const float* x2 = x + (size_t)r[2] * F_IN;
    const float* x3 = x + (size_t)r[3] * F_IN;

    float acc[4][4] = {};
#pragma unroll 4
    for (int k = 0; k < F_IN; ++k) {
        float4 w = *(const float4*)(W + (size_t)k * HID + j);
        float xv0 = x0[k], xv1 = x1[k], xv2 = x2[k], xv3 = x3[k];
        acc[0][0] += xv0 * w.x; acc[0][1] += xv0 * w.y; acc[0][2] += xv0 * w.z; acc[0][3] += xv0 * w.w;
        acc[1][0] += xv1 * w.x; acc[1][1] += xv1 * w.y; acc[1][2] += xv1 * w.z; acc[1][3] += xv1 * w.w;
        acc[2][0] += xv2 * w.x; acc[2][1] += xv2 * w.y; acc[2][2] += xv2 * w.z; acc[2][3] += xv2 * w.w;
        acc[3][0] += xv3 * w.x; acc[3][1] += xv3 * w.y; acc[3][2] += xv3 * w.z; acc[3][3] += xv3 * w.w;
    }
#pragma unroll
    for (int t = 0; t < 4; ++t) {
        int row = row0 + t;
        if (row < N_NODES) {
            float4 o = { acc[t][0], acc[t][1], acc[t][2], acc[t][3] };
            *(float4*)(h + (size_t)row * HID + j) = o;
        }
    }
}

// ---------------- GEMM2: h2[N][32] = relu(a1)[N][128] @ W2[128][32] ----------------
// 256 threads: 8 col-quads x 32 row-groups; each thread 4 rows x 4 cols. Block = 128 rows.

__global__ __launch_bounds__(256) void k_gemm2(const float* __restrict__ a,
                                               const float* __restrict__ W,
                                               float* __restrict__ h) {
    const int jq = threadIdx.x & 7;
    const int ig = threadIdx.x >> 3;
    const int j = jq * 4;
    const int row0 = blockIdx.x * 128 + ig * 4;

    int r[4];
#pragma unroll
    for (int t = 0; t < 4; ++t) r[t] = min(row0 + t, N_NODES - 1);

    const float* a0 = a + (size_t)r[0] * HID;
    const float* a1p = a + (size_t)r[1] * HID;
    const float* a2 = a + (size_t)r[2] * HID;
    const float* a3 = a + (size_t)r[3] * HID;

    float acc[4][4] = {};
#pragma unroll 4
    for (int k = 0; k < HID; ++k) {
        float4 w = *(const float4*)(W + (size_t)k * CLS + j);
        float xv0 = fmaxf(a0[k], 0.0f);
        float xv1 = fmaxf(a1p[k], 0.0f);
        float xv2 = fmaxf(a2[k], 0.0f);
        float xv3 = fmaxf(a3[k], 0.0f);
        acc[0][0] += xv0 * w.x; acc[0][1] += xv0 * w.y; acc[0][2] += xv0 * w.z; acc[0][3] += xv0 * w.w;
        acc[1][0] += xv1 * w.x; acc[1][1] += xv1 * w.y; acc[1][2] += xv1 * w.z; acc[1][3] += xv1 * w.w;
        acc[2][0] += xv2 * w.x; acc[2][1] += xv2 * w.y; acc[2][2] += xv2 * w.z; acc[2][3] += xv2 * w.w;
        acc[3][0] += xv3 * w.x; acc[3][1] += xv3 * w.y; acc[3][2] += xv3 * w.z; acc[3][3] += xv3 * w.w;
    }
#pragma unroll
    for (int t = 0; t < 4; ++t) {
        int row = row0 + t;
        if (row < N_NODES) {
            float4 o = { acc[t][0], acc[t][1], acc[t][2], acc[t][3] };
            *(float4*)(h + (size_t)row * CLS + j) = o;
        }
    }
}

// ---------------- aggregation ----------------

__global__ __launch_bounds__(256) void k_agg_init1(const float* __restrict__ h,
                                                   const float* __restrict__ dinv,
                                                   const float* __restrict__ b,
                                                   float* __restrict__ out) {
    int t = blockIdx.x * 256 + threadIdx.x;
    int idx = t * 4;
    if (idx >= N_NODES * HID) return;
    int i = idx >> 7;         // /128
    int f = idx & 127;
    float dv = dinv[i];
    float s = dv * dv;
    float4 hv = *(const float4*)(h + idx);
    float4 bv = *(const float4*)(b + f);
    float4 o = { hv.x * s + bv.x, hv.y * s + bv.y, hv.z * s + bv.z, hv.w * s + bv.w };
    *(float4*)(out + idx) = o;
}

__global__ __launch_bounds__(256) void k_scatter1(const int* __restrict__ src,
                                                  const int* __restrict__ dst,
                                                  const float* __restrict__ h,
                                                  const float* __restrict__ dinv,
                                                  float* __restrict__ out) {
    int t = blockIdx.x * 256 + threadIdx.x;
    int e = t >> 5;
    int lane = t & 31;
    if (e >= N_EDGE) return;
    int s = src[e], d = dst[e];
    float norm = dinv[s] * dinv[d];
    int f = lane * 4;
    float4 hv = *(const float4*)(h + (size_t)s * HID + f);
    float* o = out + (size_t)d * HID + f;
    atomicAdd(o + 0, hv.x * norm);
    atomicAdd(o + 1, hv.y * norm);
    atomicAdd(o + 2, hv.z * norm);
    atomicAdd(o + 3, hv.w * norm);
}

__global__ __launch_bounds__(256) void k_agg_init2(const float* __restrict__ h,
                                                   const float* __restrict__ dinv,
                                                   const float* __restrict__ b,
                                                   float* __restrict__ out) {
    int t = blockIdx.x * 256 + threadIdx.x;
    int idx = t * 4;
    if (idx >= N_NODES * CLS) return;
    int i = idx >> 5;         // /32
    int f = idx & 31;
    float dv = dinv[i];
    float s = dv * dv;
    float4 hv = *(const float4*)(h + idx);
    float4 bv = *(const float4*)(b + f);
    float4 o = { hv.x * s + bv.x, hv.y * s + bv.y, hv.z * s + bv.z, hv.w * s + bv.w };
    *(float4*)(out + idx) = o;
}

__global__ __launch_bounds__(256) void k_scatter2(const int* __restrict__ src,
                                                  const int* __restrict__ dst,
                                                  const float* __restrict__ h,
                                                  const float* __restrict__ dinv,
                                                  float* __restrict__ out) {
    int t = blockIdx.x * 256 + threadIdx.x;
    int e = t >> 3;
    int lane = t & 7;
    if (e >= N_EDGE) return;
    int s = src[e], d = dst[e];
    float norm = dinv[s] * dinv[d];
    int f = lane * 4;
    float4 hv = *(const float4*)(h + (size_t)s * CLS + f);
    float* o = out + (size_t)d * CLS + f;
    atomicAdd(o + 0, hv.x * norm);
    atomicAdd(o + 1, hv.y * norm);
    atomicAdd(o + 2, hv.z * norm);
    atomicAdd(o + 3, hv.w * norm);
}

// ---------------- log-softmax (in-place on d_out) ----------------

__global__ __launch_bounds__(256) void k_logsoftmax(float* __restrict__ out) {
    int row = blockIdx.x * 256 + threadIdx.x;
    if (row >= N_NODES) return;
    float v[CLS];
    float4* p = (float4*)(out + (size_t)row * CLS);
#pragma unroll
    for (int q = 0; q < CLS / 4; ++q) {
        float4 t = p[q];
        v[q * 4 + 0] = t.x; v[q * 4 + 1] = t.y; v[q * 4 + 2] = t.z; v[q * 4 + 3] = t.w;
    }
    float m = v[0];
#pragma unroll
    for (int j = 1; j < CLS; ++j) m = fmaxf(m, v[j]);
    float sum = 0.0f;
#pragma unroll
    for (int j = 0; j < CLS; ++j) sum += expf(v[j] - m);
    float l = m + logf(sum);
#pragma unroll
    for (int q = 0; q < CLS / 4; ++q) {
        float4 o = { v[q * 4 + 0] - l, v[q * 4 + 1] - l, v[q * 4 + 2] - l, v[q * 4 + 3] - l };
        p[q] = o;
    }
}

// ---------------- launch ----------------

extern "C" void kernel_launch(void* const* d_in, const int* in_sizes, int n_in,
                              void* d_out, int out_size, void* d_ws, size_t ws_size,
                              hipStream_t stream) {
    const float* x  = (const float*)d_in[0];
    const int*   ei = (const int*)d_in[1];
    const float* W1 = (const float*)d_in[2];
    const float* b1 = (const float*)d_in[3];
    const float* W2 = (const float*)d_in[4];
    const float* b2 = (const float*)d_in[5];
    float* out = (float*)d_out;

    const int* src = ei;
    const int* dst = ei + N_EDGE;

    float* dinv = (float*)d_ws;                          // N (padded to 50176)
    float* h1   = dinv + 50176;                          // N*HID
    float* a1   = h1 + (size_t)N_NODES * HID;            // N*HID
    float* h2   = a1 + (size_t)N_NODES * HID;            // N*CLS

    k_deg_init   <<<196,    256, 0, stream>>>(dinv);
    k_deg_scatter<<<3125,   256, 0, stream>>>(dst, dinv);
    k_rsqrt      <<<196,    256, 0, stream>>>(dinv);

    k_gemm1      <<<1563,   256, 0, stream>>>(x, W1, h1);
    k_agg_init1  <<<6250,   256, 0, stream>>>(h1, dinv, b1, a1);
    k_scatter1   <<<100000, 256, 0, stream>>>(src, dst, h1, dinv, a1);

    k_gemm2      <<<391,    256, 0, stream>>>(a1, W2, h2);
    k_agg_init2  <<<1563,   256, 0, stream>>>(h2, dinv, b2, out);
    k_scatter2   <<<25000,  256, 0, stream>>>(src, dst, h2, dinv, out);

    k_logsoftmax <<<196,    256, 0, stream>>>(out);
}

// Round 2
// 311.389 us; speedup vs baseline: 6.0147x; 6.0147x over previous
//
#include <hip/hip_runtime.h>

#define N_NODES 50000
#define N_PAD   50176      // 196 * 256
#define F_IN 256
#define HID 128
#define CLS 32
#define N_EDGE 800000

// ================= CSR build =================

__global__ __launch_bounds__(256) void k_zero(int* __restrict__ cnt, int* __restrict__ cursor) {
    int i = blockIdx.x * 256 + threadIdx.x;
    if (i < N_PAD) { cnt[i] = 0; cursor[i] = 0; }
}

__global__ __launch_bounds__(256) void k_hist(const int* __restrict__ dst, int* __restrict__ cnt) {
    int e = blockIdx.x * 256 + threadIdx.x;
    if (e < N_EDGE) atomicAdd(&cnt[dst[e]], 1);
}

// per-block exclusive scan (256 elems); writes local-exclusive to offs, block total to blksum
__global__ __launch_bounds__(256) void k_scan_block(const int* __restrict__ cnt,
                                                    int* __restrict__ offs,
                                                    int* __restrict__ blksum) {
    __shared__ int s[256];
    int tid = threadIdx.x;
    int i = blockIdx.x * 256 + tid;
    int v = cnt[i];
    s[tid] = v;
    __syncthreads();
#pragma unroll
    for (int off = 1; off < 256; off <<= 1) {
        int t = (tid >= off) ? s[tid - off] : 0;
        __syncthreads();
        s[tid] += t;
        __syncthreads();
    }
    offs[i] = s[tid] - v;              // exclusive
    if (tid == 255) blksum[blockIdx.x] = s[tid];
}

// single block: exclusive scan of 196 block sums
__global__ __launch_bounds__(256) void k_scan_top(const int* __restrict__ blksum,
                                                  int* __restrict__ blkoff) {
    __shared__ int s[256];
    int tid = threadIdx.x;
    int v = (tid < 196) ? blksum[tid] : 0;
    s[tid] = v;
    __syncthreads();
#pragma unroll
    for (int off = 1; off < 256; off <<= 1) {
        int t = (tid >= off) ? s[tid - off] : 0;
        __syncthreads();
        s[tid] += t;
        __syncthreads();
    }
    if (tid < 196) blkoff[tid] = s[tid] - v;
}

// finalize offsets (+ block offset) and dinv = rsqrt(deg+1)
__global__ __launch_bounds__(256) void k_finalize(int* __restrict__ offs,
                                                  const int* __restrict__ blkoff,
                                                  const int* __restrict__ cnt,
                                                  float* __restrict__ dinv) {
    int i = blockIdx.x * 256 + threadIdx.x;
    if (i >= N_PAD) return;
    offs[i] += blkoff[blockIdx.x];
    if (i < N_NODES) dinv[i] = rsqrtf((float)(cnt[i] + 1));
}

// place src of each edge into CSR slot of its dst
__global__ __launch_bounds__(256) void k_fill(const int* __restrict__ src,
                                              const int* __restrict__ dst,
                                              const int* __restrict__ offs,
                                              int* __restrict__ cursor,
                                              int* __restrict__ esrc) {
    int e = blockIdx.x * 256 + threadIdx.x;
    if (e >= N_EDGE) return;
    int d = dst[e];
    int pos = offs[d] + atomicAdd(&cursor[d], 1);
    esrc[pos] = src[e];
}

// ================= GEMM1: h1[N][128] = x[N][256] @ W1 =================

__global__ __launch_bounds__(256) void k_gemm1(const float* __restrict__ x,
                                               const float* __restrict__ W,
                                               float* __restrict__ h) {
    const int jq = threadIdx.x & 31;
    const int ig = threadIdx.x >> 5;
    const int j = jq * 4;
    const int row0 = blockIdx.x * 32 + ig * 4;

    int r[4];
#pragma unroll
    for (int t = 0; t < 4; ++t) r[t] = min(row0 + t, N_NODES - 1);

    const float* x0 = x + (size_t)r[0] * F_IN;
    const float* x1 = x + (size_t)r[1] * F_IN;
    const float* x2 = x + (size_t)r[2] * F_IN;
    const float* x3 = x + (size_t)r[3] * F_IN;

    float acc[4][4] = {};
#pragma unroll 4
    for (int k = 0; k < F_IN; ++k) {
        float4 w = *(const float4*)(W + (size_t)k * HID + j);
        float xv0 = x0[k], xv1 = x1[k], xv2 = x2[k], xv3 = x3[k];
        acc[0][0] += xv0 * w.x; acc[0][1] += xv0 * w.y; acc[0][2] += xv0 * w.z; acc[0][3] += xv0 * w.w;
        acc[1][0] += xv1 * w.x; acc[1][1] += xv1 * w.y; acc[1][2] += xv1 * w.z; acc[1][3] += xv1 * w.w;
        acc[2][0] += xv2 * w.x; acc[2][1] += xv2 * w.y; acc[2][2] += xv2 * w.z; acc[2][3] += xv2 * w.w;
        acc[3][0] += xv3 * w.x; acc[3][1] += xv3 * w.y; acc[3][2] += xv3 * w.z; acc[3][3] += xv3 * w.w;
    }
#pragma unroll
    for (int t = 0; t < 4; ++t) {
        int row = row0 + t;
        if (row < N_NODES) {
            float4 o = { acc[t][0], acc[t][1], acc[t][2], acc[t][3] };
            *(float4*)(h + (size_t)row * HID + j) = o;
        }
    }
}

// ================= GEMM2: h2[N][32] = relu(a1)[N][128] @ W2 =================

__global__ __launch_bounds__(256) void k_gemm2(const float* __restrict__ a,
                                               const float* __restrict__ W,
                                               float* __restrict__ h) {
    const int jq = threadIdx.x & 7;
    const int ig = threadIdx.x >> 3;
    const int j = jq * 4;
    const int row0 = blockIdx.x * 128 + ig * 4;

    int r[4];
#pragma unroll
    for (int t = 0; t < 4; ++t) r[t] = min(row0 + t, N_NODES - 1);

    const float* a0 = a + (size_t)r[0] * HID;
    const float* a1p = a + (size_t)r[1] * HID;
    const float* a2 = a + (size_t)r[2] * HID;
    const float* a3 = a + (size_t)r[3] * HID;

    float acc[4][4] = {};
#pragma unroll 4
    for (int k = 0; k < HID; ++k) {
        float4 w = *(const float4*)(W + (size_t)k * CLS + j);
        float xv0 = fmaxf(a0[k], 0.0f);
        float xv1 = fmaxf(a1p[k], 0.0f);
        float xv2 = fmaxf(a2[k], 0.0f);
        float xv3 = fmaxf(a3[k], 0.0f);
        acc[0][0] += xv0 * w.x; acc[0][1] += xv0 * w.y; acc[0][2] += xv0 * w.z; acc[0][3] += xv0 * w.w;
        acc[1][0] += xv1 * w.x; acc[1][1] += xv1 * w.y; acc[1][2] += xv1 * w.z; acc[1][3] += xv1 * w.w;
        acc[2][0] += xv2 * w.x; acc[2][1] += xv2 * w.y; acc[2][2] += xv2 * w.z; acc[2][3] += xv2 * w.w;
        acc[3][0] += xv3 * w.x; acc[3][1] += xv3 * w.y; acc[3][2] += xv3 * w.z; acc[3][3] += xv3 * w.w;
    }
#pragma unroll
    for (int t = 0; t < 4; ++t) {
        int row = row0 + t;
        if (row < N_NODES) {
            float4 o = { acc[t][0], acc[t][1], acc[t][2], acc[t][3] };
            *(float4*)(h + (size_t)row * CLS + j) = o;
        }
    }
}

// ================= gather layer 1: a1 = norm-agg(h1) + b1 =================
// 32 lanes per node, lane covers 4 consecutive features (128 = 32*4)

__global__ __launch_bounds__(256) void k_gather1(const int* __restrict__ offs,
                                                 const int* __restrict__ esrc,
                                                 const float* __restrict__ h,
                                                 const float* __restrict__ dinv,
                                                 const float* __restrict__ b,
                                                 float* __restrict__ out) {
    int node = blockIdx.x * 8 + (threadIdx.x >> 5);
    int lane = threadIdx.x & 31;
    if (node >= N_NODES) return;
    int f = lane * 4;
    float dv = dinv[node];
    float4 hv = *(const float4*)(h + (size_t)node * HID + f);
    float self = dv * dv;
    float4 acc = { hv.x * self, hv.y * self, hv.z * self, hv.w * self };
    int beg = offs[node], end = offs[node + 1];
    for (int p = beg; p < end; ++p) {
        int s = esrc[p];
        float nrm = dinv[s] * dv;
        float4 sv = *(const float4*)(h + (size_t)s * HID + f);
        acc.x += sv.x * nrm; acc.y += sv.y * nrm; acc.z += sv.z * nrm; acc.w += sv.w * nrm;
    }
    float4 bv = *(const float4*)(b + f);
    acc.x += bv.x; acc.y += bv.y; acc.z += bv.z; acc.w += bv.w;
    *(float4*)(out + (size_t)node * HID + f) = acc;
}

// ================= gather layer 2 + bias + log-softmax =================
// 8 lanes per node, lane covers 4 consecutive features (32 = 8*4)

__global__ __launch_bounds__(256) void k_gather2(const int* __restrict__ offs,
                                                 const int* __restrict__ esrc,
                                                 const float* __restrict__ h,
                                                 const float* __restrict__ dinv,
                                                 const float* __restrict__ b,
                                                 float* __restrict__ out) {
    int node = blockIdx.x * 32 + (threadIdx.x >> 3);
    int sub = threadIdx.x & 7;
    if (node >= N_NODES) return;
    int f = sub * 4;
    float dv = dinv[node];
    float4 hv = *(const float4*)(h + (size_t)node * CLS + f);
    float self = dv * dv;
    float4 acc = { hv.x * self, hv.y * self, hv.z * self, hv.w * self };
    int beg = offs[node], end = offs[node + 1];
    for (int p = beg; p < end; ++p) {
        int s = esrc[p];
        float nrm = dinv[s] * dv;
        float4 sv = *(const float4*)(h + (size_t)s * CLS + f);
        acc.x += sv.x * nrm; acc.y += sv.y * nrm; acc.z += sv.z * nrm; acc.w += sv.w * nrm;
    }
    float4 bv = *(const float4*)(b + f);
    acc.x += bv.x; acc.y += bv.y; acc.z += bv.z; acc.w += bv.w;

    // log-softmax across the 8-lane group (32 values)
    float m = fmaxf(fmaxf(acc.x, acc.y), fmaxf(acc.z, acc.w));
    m = fmaxf(m, __shfl_xor(m, 1, 8));
    m = fmaxf(m, __shfl_xor(m, 2, 8));
    m = fmaxf(m, __shfl_xor(m, 4, 8));
    float sum = expf(acc.x - m) + expf(acc.y - m) + expf(acc.z - m) + expf(acc.w - m);
    sum += __shfl_xor(sum, 1, 8);
    sum += __shfl_xor(sum, 2, 8);
    sum += __shfl_xor(sum, 4, 8);
    float l = m + logf(sum);
    float4 o = { acc.x - l, acc.y - l, acc.z - l, acc.w - l };
    *(float4*)(out + (size_t)node * CLS + f) = o;
}

// ================= launch =================

extern "C" void kernel_launch(void* const* d_in, const int* in_sizes, int n_in,
                              void* d_out, int out_size, void* d_ws, size_t ws_size,
                              hipStream_t stream) {
    const float* x  = (const float*)d_in[0];
    const int*   ei = (const int*)d_in[1];
    const float* W1 = (const float*)d_in[2];
    const float* b1 = (const float*)d_in[3];
    const float* W2 = (const float*)d_in[4];
    const float* b2 = (const float*)d_in[5];
    float* out = (float*)d_out;

    const int* src = ei;
    const int* dst = ei + N_EDGE;

    int* cnt    = (int*)d_ws;                 // N_PAD
    int* cursor = cnt + N_PAD;                // N_PAD
    int* offs   = cursor + N_PAD;             // N_PAD  (offs[N_NODES] == N_EDGE naturally)
    int* blksum = offs + N_PAD;               // 256
    int* blkoff = blksum + 256;               // 256
    int* esrc   = blkoff + 256;               // N_EDGE
    float* dinv = (float*)(esrc + N_EDGE);    // N_PAD
    float* h1   = dinv + N_PAD;               // N*HID
    float* a1   = h1 + (size_t)N_NODES * HID; // N*HID
    float* h2   = a1 + (size_t)N_NODES * HID; // N*CLS

    // CSR build
    k_zero      <<<196,  256, 0, stream>>>(cnt, cursor);
    k_hist      <<<3125, 256, 0, stream>>>(dst, cnt);
    k_scan_block<<<196,  256, 0, stream>>>(cnt, offs, blksum);
    k_scan_top  <<<1,    256, 0, stream>>>(blksum, blkoff);
    k_finalize  <<<196,  256, 0, stream>>>(offs, blkoff, cnt, dinv);
    k_fill      <<<3125, 256, 0, stream>>>(src, dst, offs, cursor, esrc);

    // layer 1
    k_gemm1   <<<1563, 256, 0, stream>>>(x, W1, h1);
    k_gather1 <<<6250, 256, 0, stream>>>(offs, esrc, h1, dinv, b1, a1);

    // layer 2 (relu fused into gemm2 read; bias+logsoftmax fused into gather2)
    k_gemm2   <<<391,  256, 0, stream>>>(a1, W2, h2);
    k_gather2 <<<1563, 256, 0, stream>>>(offs, esrc, h2, dinv, b2, out);
}

// Round 3
// 219.499 us; speedup vs baseline: 8.5327x; 1.4186x over previous
//
#include <hip/hip_runtime.h>

#define N_NODES 50000
#define N_PAD   50176      // 196 * 256
#define F_IN 256
#define HID 128
#define CLS 32
#define N_EDGE 800000

typedef short bf16x8 __attribute__((ext_vector_type(8)));
typedef float f32x4  __attribute__((ext_vector_type(4)));
typedef float f32x8  __attribute__((ext_vector_type(8)));

static __device__ inline short f2bf(float f) {
    union { float f; unsigned u; } v; v.f = f;
    unsigned r = v.u + 0x7FFFu + ((v.u >> 16) & 1u);
    return (short)(r >> 16);
}

// ================= CSR build =================

__global__ __launch_bounds__(256) void k_zero(int* __restrict__ cnt, int* __restrict__ cursor) {
    int i = blockIdx.x * 256 + threadIdx.x;
    if (i < N_PAD) { cnt[i] = 0; cursor[i] = 0; }
}

__global__ __launch_bounds__(256) void k_hist(const int* __restrict__ dst, int* __restrict__ cnt) {
    int e = blockIdx.x * 256 + threadIdx.x;
    if (e < N_EDGE) atomicAdd(&cnt[dst[e]], 1);
}

__global__ __launch_bounds__(256) void k_scan_block(const int* __restrict__ cnt,
                                                    int* __restrict__ offs,
                                                    int* __restrict__ blksum) {
    __shared__ int s[256];
    int tid = threadIdx.x;
    int i = blockIdx.x * 256 + tid;
    int v = cnt[i];
    s[tid] = v;
    __syncthreads();
#pragma unroll
    for (int off = 1; off < 256; off <<= 1) {
        int t = (tid >= off) ? s[tid - off] : 0;
        __syncthreads();
        s[tid] += t;
        __syncthreads();
    }
    offs[i] = s[tid] - v;              // exclusive
    if (tid == 255) blksum[blockIdx.x] = s[tid];
}

__global__ __launch_bounds__(256) void k_scan_top(const int* __restrict__ blksum,
                                                  int* __restrict__ blkoff) {
    __shared__ int s[256];
    int tid = threadIdx.x;
    int v = (tid < 196) ? blksum[tid] : 0;
    s[tid] = v;
    __syncthreads();
#pragma unroll
    for (int off = 1; off < 256; off <<= 1) {
        int t = (tid >= off) ? s[tid - off] : 0;
        __syncthreads();
        s[tid] += t;
        __syncthreads();
    }
    if (tid < 196) blkoff[tid] = s[tid] - v;
}

__global__ __launch_bounds__(256) void k_finalize(int* __restrict__ offs,
                                                  const int* __restrict__ blkoff,
                                                  const int* __restrict__ cnt,
                                                  float* __restrict__ dinv) {
    int i = blockIdx.x * 256 + threadIdx.x;
    if (i >= N_PAD) return;
    offs[i] += blkoff[blockIdx.x];
    if (i < N_NODES) dinv[i] = rsqrtf((float)(cnt[i] + 1));
}

__global__ __launch_bounds__(256) void k_fill(const int* __restrict__ src,
                                              const int* __restrict__ dst,
                                              const int* __restrict__ offs,
                                              int* __restrict__ cursor,
                                              int* __restrict__ esrc) {
    int e = blockIdx.x * 256 + threadIdx.x;
    if (e >= N_EDGE) return;
    int d = dst[e];
    int pos = offs[d] + atomicAdd(&cursor[d], 1);
    esrc[pos] = src[e];
}

// ================= W1 transpose+convert: Wt[n][k] bf16, n<128, k<256 =================

__global__ __launch_bounds__(256) void k_wcvt(const float* __restrict__ W,
                                              short* __restrict__ Wt) {
    int idx = blockIdx.x * 256 + threadIdx.x;   // 32768
    int k = idx >> 7;
    int n = idx & 127;
    Wt[n * F_IN + k] = f2bf(W[(size_t)k * HID + n]);
}

// ================= GEMM1 via MFMA: h1[N][128] = x[N][256] @ W1 =================
// block = 4 waves; wave w handles rows [blk*128 + w*32, +32), all 128 cols.
// mfma_f32_16x16x32_bf16: A row=lane&15, k=8*(lane>>4)+e; B col=lane&15, same k;
// D: n=lane&15, m=4*(lane>>4)+reg.

__global__ __launch_bounds__(256) void k_gemm1_mfma(const float* __restrict__ x,
                                                    const short* __restrict__ Wt,
                                                    float* __restrict__ h) {
    const int lane = threadIdx.x & 63;
    const int w    = threadIdx.x >> 6;
    const int l15  = lane & 15;
    const int lk   = lane >> 4;           // 0..3
    const int row0 = blockIdx.x * 128 + w * 32;

    f32x4 acc[2][8] = {};

#pragma unroll
    for (int ks = 0; ks < F_IN / 32; ++ks) {
        const int kbase = ks * 32 + lk * 8;

        bf16x8 afrag[2];
#pragma unroll
        for (int mt = 0; mt < 2; ++mt) {
            int row = row0 + mt * 16 + l15;
            row = min(row, N_NODES - 1);
            f32x8 xv = *(const f32x8*)(x + (size_t)row * F_IN + kbase);
            bf16x8 a;
#pragma unroll
            for (int e = 0; e < 8; ++e) a[e] = f2bf(xv[e]);
            afrag[mt] = a;
        }

        bf16x8 bfrag[8];
#pragma unroll
        for (int nt = 0; nt < 8; ++nt) {
            int col = nt * 16 + l15;
            bfrag[nt] = *(const bf16x8*)(Wt + (size_t)col * F_IN + kbase);
        }

#pragma unroll
        for (int mt = 0; mt < 2; ++mt)
#pragma unroll
            for (int nt = 0; nt < 8; ++nt)
                acc[mt][nt] = __builtin_amdgcn_mfma_f32_16x16x32_bf16(
                    afrag[mt], bfrag[nt], acc[mt][nt], 0, 0, 0);
    }

#pragma unroll
    for (int mt = 0; mt < 2; ++mt) {
#pragma unroll
        for (int r = 0; r < 4; ++r) {
            int m = row0 + mt * 16 + lk * 4 + r;
            if (m < N_NODES) {
#pragma unroll
                for (int nt = 0; nt < 8; ++nt) {
                    int n = nt * 16 + l15;
                    h[(size_t)m * HID + n] = acc[mt][nt][r];
                }
            }
        }
    }
}

// ================= GEMM2: h2[N][32] = relu(a1)[N][128] @ W2 =================

__global__ __launch_bounds__(256) void k_gemm2(const float* __restrict__ a,
                                               const float* __restrict__ W,
                                               float* __restrict__ h) {
    const int jq = threadIdx.x & 7;
    const int ig = threadIdx.x >> 3;
    const int j = jq * 4;
    const int row0 = blockIdx.x * 128 + ig * 4;

    int r[4];
#pragma unroll
    for (int t = 0; t < 4; ++t) r[t] = min(row0 + t, N_NODES - 1);

    const float* a0 = a + (size_t)r[0] * HID;
    const float* a1p = a + (size_t)r[1] * HID;
    const float* a2 = a + (size_t)r[2] * HID;
    const float* a3 = a + (size_t)r[3] * HID;

    float acc[4][4] = {};
#pragma unroll 4
    for (int k = 0; k < HID; ++k) {
        float4 w = *(const float4*)(W + (size_t)k * CLS + j);
        float xv0 = fmaxf(a0[k], 0.0f);
        float xv1 = fmaxf(a1p[k], 0.0f);
        float xv2 = fmaxf(a2[k], 0.0f);
        float xv3 = fmaxf(a3[k], 0.0f);
        acc[0][0] += xv0 * w.x; acc[0][1] += xv0 * w.y; acc[0][2] += xv0 * w.z; acc[0][3] += xv0 * w.w;
        acc[1][0] += xv1 * w.x; acc[1][1] += xv1 * w.y; acc[1][2] += xv1 * w.z; acc[1][3] += xv1 * w.w;
        acc[2][0] += xv2 * w.x; acc[2][1] += xv2 * w.y; acc[2][2] += xv2 * w.z; acc[2][3] += xv2 * w.w;
        acc[3][0] += xv3 * w.x; acc[3][1] += xv3 * w.y; acc[3][2] += xv3 * w.z; acc[3][3] += xv3 * w.w;
    }
#pragma unroll
    for (int t = 0; t < 4; ++t) {
        int row = row0 + t;
        if (row < N_NODES) {
            float4 o = { acc[t][0], acc[t][1], acc[t][2], acc[t][3] };
            *(float4*)(h + (size_t)row * CLS + j) = o;
        }
    }
}

// ================= gather layer 1 (4-wide edge unroll) =================

__global__ __launch_bounds__(256) void k_gather1(const int* __restrict__ offs,
                                                 const int* __restrict__ esrc,
                                                 const float* __restrict__ h,
                                                 const float* __restrict__ dinv,
                                                 const float* __restrict__ b,
                                                 float* __restrict__ out) {
    int node = blockIdx.x * 8 + (threadIdx.x >> 5);
    int lane = threadIdx.x & 31;
    if (node >= N_NODES) return;
    int f = lane * 4;
    float dv = dinv[node];
    float4 hv = *(const float4*)(h + (size_t)node * HID + f);
    float self = dv * dv;
    float4 acc = { hv.x * self, hv.y * self, hv.z * self, hv.w * self };
    int beg = offs[node], end = offs[node + 1];
    int p = beg;
    for (; p + 3 < end; p += 4) {
        int s0 = esrc[p + 0], s1 = esrc[p + 1], s2 = esrc[p + 2], s3 = esrc[p + 3];
        float n0 = dinv[s0] * dv, n1 = dinv[s1] * dv, n2 = dinv[s2] * dv, n3 = dinv[s3] * dv;
        float4 v0 = *(const float4*)(h + (size_t)s0 * HID + f);
        float4 v1 = *(const float4*)(h + (size_t)s1 * HID + f);
        float4 v2 = *(const float4*)(h + (size_t)s2 * HID + f);
        float4 v3 = *(const float4*)(h + (size_t)s3 * HID + f);
        acc.x += v0.x * n0 + v1.x * n1 + v2.x * n2 + v3.x * n3;
        acc.y += v0.y * n0 + v1.y * n1 + v2.y * n2 + v3.y * n3;
        acc.z += v0.z * n0 + v1.z * n1 + v2.z * n2 + v3.z * n3;
        acc.w += v0.w * n0 + v1.w * n1 + v2.w * n2 + v3.w * n3;
    }
    for (; p < end; ++p) {
        int s = esrc[p];
        float nrm = dinv[s] * dv;
        float4 sv = *(const float4*)(h + (size_t)s * HID + f);
        acc.x += sv.x * nrm; acc.y += sv.y * nrm; acc.z += sv.z * nrm; acc.w += sv.w * nrm;
    }
    float4 bv = *(const float4*)(b + f);
    acc.x += bv.x; acc.y += bv.y; acc.z += bv.z; acc.w += bv.w;
    *(float4*)(out + (size_t)node * HID + f) = acc;
}

// ================= gather layer 2 + bias + log-softmax =================

__global__ __launch_bounds__(256) void k_gather2(const int* __restrict__ offs,
                                                 const int* __restrict__ esrc,
                                                 const float* __restrict__ h,
                                                 const float* __restrict__ dinv,
                                                 const float* __restrict__ b,
                                                 float* __restrict__ out) {
    int node = blockIdx.x * 32 + (threadIdx.x >> 3);
    int sub = threadIdx.x & 7;
    if (node >= N_NODES) return;
    int f = sub * 4;
    float dv = dinv[node];
    float4 hv = *(const float4*)(h + (size_t)node * CLS + f);
    float self = dv * dv;
    float4 acc = { hv.x * self, hv.y * self, hv.z * self, hv.w * self };
    int beg = offs[node], end = offs[node + 1];
    int p = beg;
    for (; p + 1 < end; p += 2) {
        int s0 = esrc[p], s1 = esrc[p + 1];
        float n0 = dinv[s0] * dv, n1 = dinv[s1] * dv;
        float4 v0 = *(const float4*)(h + (size_t)s0 * CLS + f);
        float4 v1 = *(const float4*)(h + (size_t)s1 * CLS + f);
        acc.x += v0.x * n0 + v1.x * n1;
        acc.y += v0.y * n0 + v1.y * n1;
        acc.z += v0.z * n0 + v1.z * n1;
        acc.w += v0.w * n0 + v1.w * n1;
    }
    if (p < end) {
        int s = esrc[p];
        float nrm = dinv[s] * dv;
        float4 sv = *(const float4*)(h + (size_t)s * CLS + f);
        acc.x += sv.x * nrm; acc.y += sv.y * nrm; acc.z += sv.z * nrm; acc.w += sv.w * nrm;
    }
    float4 bv = *(const float4*)(b + f);
    acc.x += bv.x; acc.y += bv.y; acc.z += bv.z; acc.w += bv.w;

    float m = fmaxf(fmaxf(acc.x, acc.y), fmaxf(acc.z, acc.w));
    m = fmaxf(m, __shfl_xor(m, 1, 8));
    m = fmaxf(m, __shfl_xor(m, 2, 8));
    m = fmaxf(m, __shfl_xor(m, 4, 8));
    float sum = expf(acc.x - m) + expf(acc.y - m) + expf(acc.z - m) + expf(acc.w - m);
    sum += __shfl_xor(sum, 1, 8);
    sum += __shfl_xor(sum, 2, 8);
    sum += __shfl_xor(sum, 4, 8);
    float l = m + logf(sum);
    float4 o = { acc.x - l, acc.y - l, acc.z - l, acc.w - l };
    *(float4*)(out + (size_t)node * CLS + f) = o;
}

// ================= launch =================

extern "C" void kernel_launch(void* const* d_in, const int* in_sizes, int n_in,
                              void* d_out, int out_size, void* d_ws, size_t ws_size,
                              hipStream_t stream) {
    const float* x  = (const float*)d_in[0];
    const int*   ei = (const int*)d_in[1];
    const float* W1 = (const float*)d_in[2];
    const float* b1 = (const float*)d_in[3];
    const float* W2 = (const float*)d_in[4];
    const float* b2 = (const float*)d_in[5];
    float* out = (float*)d_out;

    const int* src = ei;
    const int* dst = ei + N_EDGE;

    int* cnt    = (int*)d_ws;                 // N_PAD
    int* cursor = cnt + N_PAD;                // N_PAD
    int* offs   = cursor + N_PAD;             // N_PAD (offs[N_NODES] == N_EDGE)
    int* blksum = offs + N_PAD;               // 256
    int* blkoff = blksum + 256;               // 256
    int* esrc   = blkoff + 256;               // N_EDGE
    float* dinv = (float*)(esrc + N_EDGE);    // N_PAD
    short* Wt   = (short*)(dinv + N_PAD);     // 128*256 bf16 (32768 shorts)
    float* h1   = (float*)(Wt + HID * F_IN);  // N*HID
    float* a1   = h1 + (size_t)N_NODES * HID; // N*HID
    float* h2   = a1 + (size_t)N_NODES * HID; // N*CLS

    // CSR build + weight convert
    k_zero      <<<196,  256, 0, stream>>>(cnt, cursor);
    k_hist      <<<3125, 256, 0, stream>>>(dst, cnt);
    k_scan_block<<<196,  256, 0, stream>>>(cnt, offs, blksum);
    k_scan_top  <<<1,    256, 0, stream>>>(blksum, blkoff);
    k_finalize  <<<196,  256, 0, stream>>>(offs, blkoff, cnt, dinv);
    k_fill      <<<3125, 256, 0, stream>>>(src, dst, offs, cursor, esrc);
    k_wcvt      <<<128,  256, 0, stream>>>(W1, Wt);

    // layer 1
    k_gemm1_mfma<<<391,  256, 0, stream>>>(x, Wt, h1);
    k_gather1   <<<6250, 256, 0, stream>>>(offs, esrc, h1, dinv, b1, a1);

    // layer 2
    k_gemm2     <<<391,  256, 0, stream>>>(a1, W2, h2);
    k_gather2   <<<1563, 256, 0, stream>>>(offs, esrc, h2, dinv, b2, out);
}

// Round 4
// 197.241 us; speedup vs baseline: 9.4956x; 1.1128x over previous
//
#include <hip/hip_runtime.h>

#define N_NODES 50000
#define N_PAD   50176      // 196 * 256
#define F_IN 256
#define HID 128
#define CLS 32
#define N_EDGE 800000

typedef short bf16x8 __attribute__((ext_vector_type(8)));
typedef short s16x4  __attribute__((ext_vector_type(4)));
typedef float f32x4  __attribute__((ext_vector_type(4)));
typedef float f32x8  __attribute__((ext_vector_type(8)));

static __device__ inline short f2bf(float f) {
    union { float f; unsigned u; } v; v.f = f;
    unsigned r = v.u + 0x7FFFu + ((v.u >> 16) & 1u);
    return (short)(r >> 16);
}

static __device__ inline float bf2f(short b) {
    union { unsigned u; float f; } v;
    v.u = ((unsigned)(unsigned short)b) << 16;
    return v.f;
}

// ================= CSR build =================

__global__ __launch_bounds__(256) void k_zero(int* __restrict__ cnt, int* __restrict__ cursor) {
    int i = blockIdx.x * 256 + threadIdx.x;
    if (i < N_PAD) { cnt[i] = 0; cursor[i] = 0; }
}

__global__ __launch_bounds__(256) void k_hist(const int* __restrict__ dst, int* __restrict__ cnt) {
    int e = blockIdx.x * 256 + threadIdx.x;
    if (e < N_EDGE) atomicAdd(&cnt[dst[e]], 1);
}

__global__ __launch_bounds__(256) void k_scan_block(const int* __restrict__ cnt,
                                                    int* __restrict__ offs,
                                                    int* __restrict__ blksum) {
    __shared__ int s[256];
    int tid = threadIdx.x;
    int i = blockIdx.x * 256 + tid;
    int v = cnt[i];
    s[tid] = v;
    __syncthreads();
#pragma unroll
    for (int off = 1; off < 256; off <<= 1) {
        int t = (tid >= off) ? s[tid - off] : 0;
        __syncthreads();
        s[tid] += t;
        __syncthreads();
    }
    offs[i] = s[tid] - v;              // exclusive
    if (tid == 255) blksum[blockIdx.x] = s[tid];
}

__global__ __launch_bounds__(256) void k_scan_top(const int* __restrict__ blksum,
                                                  int* __restrict__ blkoff) {
    __shared__ int s[256];
    int tid = threadIdx.x;
    int v = (tid < 196) ? blksum[tid] : 0;
    s[tid] = v;
    __syncthreads();
#pragma unroll
    for (int off = 1; off < 256; off <<= 1) {
        int t = (tid >= off) ? s[tid - off] : 0;
        __syncthreads();
        s[tid] += t;
        __syncthreads();
    }
    if (tid < 196) blkoff[tid] = s[tid] - v;
}

__global__ __launch_bounds__(256) void k_finalize(int* __restrict__ offs,
                                                  const int* __restrict__ blkoff,
                                                  const int* __restrict__ cnt,
                                                  float* __restrict__ dinv) {
    int i = blockIdx.x * 256 + threadIdx.x;
    if (i >= N_PAD) return;
    offs[i] += blkoff[blockIdx.x];
    if (i < N_NODES) dinv[i] = rsqrtf((float)(cnt[i] + 1));
}

__global__ __launch_bounds__(256) void k_fill(const int* __restrict__ src,
                                              const int* __restrict__ dst,
                                              const int* __restrict__ offs,
                                              int* __restrict__ cursor,
                                              int* __restrict__ esrc) {
    int e = blockIdx.x * 256 + threadIdx.x;
    if (e >= N_EDGE) return;
    int d = dst[e];
    int pos = offs[d] + atomicAdd(&cursor[d], 1);
    esrc[pos] = src[e];
}

// ================= W1 transpose+convert: Wt[n][k] bf16 =================

__global__ __launch_bounds__(256) void k_wcvt(const float* __restrict__ W,
                                              short* __restrict__ Wt) {
    int idx = blockIdx.x * 256 + threadIdx.x;   // 32768
    int k = idx >> 7;
    int n = idx & 127;
    Wt[n * F_IN + k] = f2bf(W[(size_t)k * HID + n]);
}

// ================= GEMM1 via MFMA: h1[N][128] (bf16) = x @ W1 =================

__global__ __launch_bounds__(256) void k_gemm1_mfma(const float* __restrict__ x,
                                                    const short* __restrict__ Wt,
                                                    short* __restrict__ h) {
    const int lane = threadIdx.x & 63;
    const int w    = threadIdx.x >> 6;
    const int l15  = lane & 15;
    const int lk   = lane >> 4;           // 0..3
    const int row0 = blockIdx.x * 128 + w * 32;

    f32x4 acc[2][8] = {};

#pragma unroll
    for (int ks = 0; ks < F_IN / 32; ++ks) {
        const int kbase = ks * 32 + lk * 8;

        bf16x8 afrag[2];
#pragma unroll
        for (int mt = 0; mt < 2; ++mt) {
            int row = row0 + mt * 16 + l15;
            row = min(row, N_NODES - 1);
            f32x8 xv = *(const f32x8*)(x + (size_t)row * F_IN + kbase);
            bf16x8 a;
#pragma unroll
            for (int e = 0; e < 8; ++e) a[e] = f2bf(xv[e]);
            afrag[mt] = a;
        }

        bf16x8 bfrag[8];
#pragma unroll
        for (int nt = 0; nt < 8; ++nt) {
            int col = nt * 16 + l15;
            bfrag[nt] = *(const bf16x8*)(Wt + (size_t)col * F_IN + kbase);
        }

#pragma unroll
        for (int mt = 0; mt < 2; ++mt)
#pragma unroll
            for (int nt = 0; nt < 8; ++nt)
                acc[mt][nt] = __builtin_amdgcn_mfma_f32_16x16x32_bf16(
                    afrag[mt], bfrag[nt], acc[mt][nt], 0, 0, 0);
    }

#pragma unroll
    for (int mt = 0; mt < 2; ++mt) {
#pragma unroll
        for (int r = 0; r < 4; ++r) {
            int m = row0 + mt * 16 + lk * 4 + r;
            if (m < N_NODES) {
#pragma unroll
                for (int nt = 0; nt < 8; ++nt) {
                    int n = nt * 16 + l15;
                    h[(size_t)m * HID + n] = f2bf(acc[mt][nt][r]);
                }
            }
        }
    }
}

// ================= GEMM2: h2[N][32] (bf16) = relu(a1)[N][128] @ W2 =================

__global__ __launch_bounds__(256) void k_gemm2(const float* __restrict__ a,
                                               const float* __restrict__ W,
                                               short* __restrict__ h) {
    const int jq = threadIdx.x & 7;
    const int ig = threadIdx.x >> 3;
    const int j = jq * 4;
    const int row0 = blockIdx.x * 128 + ig * 4;

    int r[4];
#pragma unroll
    for (int t = 0; t < 4; ++t) r[t] = min(row0 + t, N_NODES - 1);

    const float* a0 = a + (size_t)r[0] * HID;
    const float* a1p = a + (size_t)r[1] * HID;
    const float* a2 = a + (size_t)r[2] * HID;
    const float* a3 = a + (size_t)r[3] * HID;

    float acc[4][4] = {};
#pragma unroll 4
    for (int k = 0; k < HID; ++k) {
        float4 w = *(const float4*)(W + (size_t)k * CLS + j);
        float xv0 = fmaxf(a0[k], 0.0f);
        float xv1 = fmaxf(a1p[k], 0.0f);
        float xv2 = fmaxf(a2[k], 0.0f);
        float xv3 = fmaxf(a3[k], 0.0f);
        acc[0][0] += xv0 * w.x; acc[0][1] += xv0 * w.y; acc[0][2] += xv0 * w.z; acc[0][3] += xv0 * w.w;
        acc[1][0] += xv1 * w.x; acc[1][1] += xv1 * w.y; acc[1][2] += xv1 * w.z; acc[1][3] += xv1 * w.w;
        acc[2][0] += xv2 * w.x; acc[2][1] += xv2 * w.y; acc[2][2] += xv2 * w.z; acc[2][3] += xv2 * w.w;
        acc[3][0] += xv3 * w.x; acc[3][1] += xv3 * w.y; acc[3][2] += xv3 * w.z; acc[3][3] += xv3 * w.w;
    }
#pragma unroll
    for (int t = 0; t < 4; ++t) {
        int row = row0 + t;
        if (row < N_NODES) {
            s16x4 o = { f2bf(acc[t][0]), f2bf(acc[t][1]), f2bf(acc[t][2]), f2bf(acc[t][3]) };
            *(s16x4*)(h + (size_t)row * CLS + j) = o;
        }
    }
}

// ================= gather layer 1 (bf16 rows, 4-wide edge unroll) =================

__global__ __launch_bounds__(256) void k_gather1(const int* __restrict__ offs,
                                                 const int* __restrict__ esrc,
                                                 const short* __restrict__ h,
                                                 const float* __restrict__ dinv,
                                                 const float* __restrict__ b,
                                                 float* __restrict__ out) {
    int node = blockIdx.x * 8 + (threadIdx.x >> 5);
    int lane = threadIdx.x & 31;
    if (node >= N_NODES) return;
    int f = lane * 4;
    float dv = dinv[node];
    s16x4 hv = *(const s16x4*)(h + (size_t)node * HID + f);
    float self = dv * dv;
    float4 acc = { bf2f(hv[0]) * self, bf2f(hv[1]) * self, bf2f(hv[2]) * self, bf2f(hv[3]) * self };
    int beg = offs[node], end = offs[node + 1];
    int p = beg;
    for (; p + 3 < end; p += 4) {
        int s0 = esrc[p + 0], s1 = esrc[p + 1], s2 = esrc[p + 2], s3 = esrc[p + 3];
        float n0 = dinv[s0] * dv, n1 = dinv[s1] * dv, n2 = dinv[s2] * dv, n3 = dinv[s3] * dv;
        s16x4 v0 = *(const s16x4*)(h + (size_t)s0 * HID + f);
        s16x4 v1 = *(const s16x4*)(h + (size_t)s1 * HID + f);
        s16x4 v2 = *(const s16x4*)(h + (size_t)s2 * HID + f);
        s16x4 v3 = *(const s16x4*)(h + (size_t)s3 * HID + f);
        acc.x += bf2f(v0[0]) * n0 + bf2f(v1[0]) * n1 + bf2f(v2[0]) * n2 + bf2f(v3[0]) * n3;
        acc.y += bf2f(v0[1]) * n0 + bf2f(v1[1]) * n1 + bf2f(v2[1]) * n2 + bf2f(v3[1]) * n3;
        acc.z += bf2f(v0[2]) * n0 + bf2f(v1[2]) * n1 + bf2f(v2[2]) * n2 + bf2f(v3[2]) * n3;
        acc.w += bf2f(v0[3]) * n0 + bf2f(v1[3]) * n1 + bf2f(v2[3]) * n2 + bf2f(v3[3]) * n3;
    }
    for (; p < end; ++p) {
        int s = esrc[p];
        float nrm = dinv[s] * dv;
        s16x4 sv = *(const s16x4*)(h + (size_t)s * HID + f);
        acc.x += bf2f(sv[0]) * nrm; acc.y += bf2f(sv[1]) * nrm;
        acc.z += bf2f(sv[2]) * nrm; acc.w += bf2f(sv[3]) * nrm;
    }
    float4 bv = *(const float4*)(b + f);
    acc.x += bv.x; acc.y += bv.y; acc.z += bv.z; acc.w += bv.w;
    *(float4*)(out + (size_t)node * HID + f) = acc;
}

// ================= gather layer 2 (bf16 rows) + bias + log-softmax =================

__global__ __launch_bounds__(256) void k_gather2(const int* __restrict__ offs,
                                                 const int* __restrict__ esrc,
                                                 const short* __restrict__ h,
                                                 const float* __restrict__ dinv,
                                                 const float* __restrict__ b,
                                                 float* __restrict__ out) {
    int node = blockIdx.x * 32 + (threadIdx.x >> 3);
    int sub = threadIdx.x & 7;
    if (node >= N_NODES) return;
    int f = sub * 4;
    float dv = dinv[node];
    s16x4 hv = *(const s16x4*)(h + (size_t)node * CLS + f);
    float self = dv * dv;
    float4 acc = { bf2f(hv[0]) * self, bf2f(hv[1]) * self, bf2f(hv[2]) * self, bf2f(hv[3]) * self };
    int beg = offs[node], end = offs[node + 1];
    int p = beg;
    for (; p + 1 < end; p += 2) {
        int s0 = esrc[p], s1 = esrc[p + 1];
        float n0 = dinv[s0] * dv, n1 = dinv[s1] * dv;
        s16x4 v0 = *(const s16x4*)(h + (size_t)s0 * CLS + f);
        s16x4 v1 = *(const s16x4*)(h + (size_t)s1 * CLS + f);
        acc.x += bf2f(v0[0]) * n0 + bf2f(v1[0]) * n1;
        acc.y += bf2f(v0[1]) * n0 + bf2f(v1[1]) * n1;
        acc.z += bf2f(v0[2]) * n0 + bf2f(v1[2]) * n1;
        acc.w += bf2f(v0[3]) * n0 + bf2f(v1[3]) * n1;
    }
    if (p < end) {
        int s = esrc[p];
        float nrm = dinv[s] * dv;
        s16x4 sv = *(const s16x4*)(h + (size_t)s * CLS + f);
        acc.x += bf2f(sv[0]) * nrm; acc.y += bf2f(sv[1]) * nrm;
        acc.z += bf2f(sv[2]) * nrm; acc.w += bf2f(sv[3]) * nrm;
    }
    float4 bv = *(const float4*)(b + f);
    acc.x += bv.x; acc.y += bv.y; acc.z += bv.z; acc.w += bv.w;

    float m = fmaxf(fmaxf(acc.x, acc.y), fmaxf(acc.z, acc.w));
    m = fmaxf(m, __shfl_xor(m, 1, 8));
    m = fmaxf(m, __shfl_xor(m, 2, 8));
    m = fmaxf(m, __shfl_xor(m, 4, 8));
    float sum = expf(acc.x - m) + expf(acc.y - m) + expf(acc.z - m) + expf(acc.w - m);
    sum += __shfl_xor(sum, 1, 8);
    sum += __shfl_xor(sum, 2, 8);
    sum += __shfl_xor(sum, 4, 8);
    float l = m + logf(sum);
    float4 o = { acc.x - l, acc.y - l, acc.z - l, acc.w - l };
    *(float4*)(out + (size_t)node * CLS + f) = o;
}

// ================= launch =================

extern "C" void kernel_launch(void* const* d_in, const int* in_sizes, int n_in,
                              void* d_out, int out_size, void* d_ws, size_t ws_size,
                              hipStream_t stream) {
    const float* x  = (const float*)d_in[0];
    const int*   ei = (const int*)d_in[1];
    const float* W1 = (const float*)d_in[2];
    const float* b1 = (const float*)d_in[3];
    const float* W2 = (const float*)d_in[4];
    const float* b2 = (const float*)d_in[5];
    float* out = (float*)d_out;

    const int* src = ei;
    const int* dst = ei + N_EDGE;

    int* cnt    = (int*)d_ws;                   // N_PAD
    int* cursor = cnt + N_PAD;                  // N_PAD
    int* offs   = cursor + N_PAD;               // N_PAD (offs[N_NODES] == N_EDGE)
    int* blksum = offs + N_PAD;                 // 256
    int* blkoff = blksum + 256;                 // 256
    int* esrc   = blkoff + 256;                 // N_EDGE
    float* dinv = (float*)(esrc + N_EDGE);      // N_PAD
    short* Wt   = (short*)(dinv + N_PAD);       // 128*256 bf16
    short* h1   = Wt + HID * F_IN;              // N*HID bf16
    float* a1   = (float*)(h1 + (size_t)N_NODES * HID);  // N*HID f32
    short* h2   = (short*)(a1 + (size_t)N_NODES * HID);  // N*CLS bf16

    // CSR build + weight convert
    k_zero      <<<196,  256, 0, stream>>>(cnt, cursor);
    k_hist      <<<3125, 256, 0, stream>>>(dst, cnt);
    k_scan_block<<<196,  256, 0, stream>>>(cnt, offs, blksum);
    k_scan_top  <<<1,    256, 0, stream>>>(blksum, blkoff);
    k_finalize  <<<196,  256, 0, stream>>>(offs, blkoff, cnt, dinv);
    k_fill      <<<3125, 256, 0, stream>>>(src, dst, offs, cursor, esrc);
    k_wcvt      <<<128,  256, 0, stream>>>(W1, Wt);

    // layer 1
    k_gemm1_mfma<<<391,  256, 0, stream>>>(x, Wt, h1);
    k_gather1   <<<6250, 256, 0, stream>>>(offs, esrc, h1, dinv, b1, a1);

    // layer 2
    k_gemm2     <<<391,  256, 0, stream>>>(a1, W2, h2);
    k_gather2   <<<1563, 256, 0, stream>>>(offs, esrc, h2, dinv, b2, out);
}

// Round 5
// 154.336 us; speedup vs baseline: 12.1353x; 1.2780x over previous
//
#include <hip/hip_runtime.h>

#define N_NODES 50000
#define N_PAD   50176      // 196 * 256
#define F_IN 256
#define HID 128
#define CLS 32
#define N_EDGE 800000

#define NB    196          // edge chunks / blocks for multisplit
#define NPART 196          // partitions of 256 nodes
#define CHUNK 4082         // ceil(800000/196)

typedef short bf16x8 __attribute__((ext_vector_type(8)));
typedef short s16x4  __attribute__((ext_vector_type(4)));
typedef float f32x4  __attribute__((ext_vector_type(4)));
typedef float f32x8  __attribute__((ext_vector_type(8)));

static __device__ inline short f2bf(float f) {
    union { float f; unsigned u; } v; v.f = f;
    unsigned r = v.u + 0x7FFFu + ((v.u >> 16) & 1u);
    return (short)(r >> 16);
}

static __device__ inline float bf2f(short b) {
    union { unsigned u; float f; } v;
    v.u = ((unsigned)(unsigned short)b) << 16;
    return v.f;
}

// ================= multisplit CSR build =================

// pass A: per-block coarse histogram (partition = dst>>8)
__global__ __launch_bounds__(256) void k_histA(const int* __restrict__ dst,
                                               int* __restrict__ counts) {
    __shared__ int hist[NPART];
    int tid = threadIdx.x, blk = blockIdx.x;
    if (tid < NPART) hist[tid] = 0;
    __syncthreads();
    int lo = blk * CHUNK, hi = min(lo + CHUNK, N_EDGE);
    for (int e = lo + tid; e < hi; e += 256)
        atomicAdd(&hist[dst[e] >> 8], 1);
    __syncthreads();
    if (tid < NPART) counts[blk * NPART + tid] = hist[tid];
}

// pass B: scan -> private (block,part) output runs; partbase
__global__ __launch_bounds__(256) void k_scanA(const int* __restrict__ counts,
                                               int* __restrict__ base,
                                               int* __restrict__ partbase) {
    __shared__ int s[256];
    int tid = threadIdx.x;
    int tot = 0;
    if (tid < NPART) {
        int run = 0;
        for (int b = 0; b < NB; ++b) {
            int c = counts[b * NPART + tid];
            base[b * NPART + tid] = run;
            run += c;
        }
        tot = run;
    }
    s[tid] = tot;
    __syncthreads();
#pragma unroll
    for (int off = 1; off < 256; off <<= 1) {
        int t = (tid >= off) ? s[tid - off] : 0;
        __syncthreads();
        s[tid] += t;
        __syncthreads();
    }
    int excl = s[tid] - tot;
    if (tid <= NPART) partbase[tid] = excl;
    if (tid < NPART) {
        for (int b = 0; b < NB; ++b) base[b * NPART + tid] += excl;
    }
}

// pass C: bucket edges into private runs, packed (d8<<16)|src
__global__ __launch_bounds__(256) void k_bucket(const int* __restrict__ src,
                                                const int* __restrict__ dst,
                                                const int* __restrict__ base,
                                                int* __restrict__ bucket) {
    __shared__ int cur[NPART];
    int tid = threadIdx.x, blk = blockIdx.x;
    if (tid < NPART) cur[tid] = base[blk * NPART + tid];
    __syncthreads();
    int lo = blk * CHUNK, hi = min(lo + CHUNK, N_EDGE);
    for (int e = lo + tid; e < hi; e += 256) {
        int d = dst[e], s = src[e];
        int pos = atomicAdd(&cur[d >> 8], 1);
        bucket[pos] = ((d & 255) << 16) | s;
    }
}

// pass D: per-partition 256-bin sort; emit esrc, offs, dinv
__global__ __launch_bounds__(256) void k_csr_final(const int* __restrict__ bucket,
                                                   const int* __restrict__ partbase,
                                                   int* __restrict__ esrc,
                                                   int* __restrict__ offs,
                                                   float* __restrict__ dinv) {
    __shared__ int hist[256], s[256], cur[256];
    int tid = threadIdx.x, p = blockIdx.x;
    int beg = partbase[p], end = partbase[p + 1];
    hist[tid] = 0;
    __syncthreads();
    for (int i = beg + tid; i < end; i += 256)
        atomicAdd(&hist[bucket[i] >> 16], 1);
    __syncthreads();
    int v = hist[tid];
    s[tid] = v;
    __syncthreads();
#pragma unroll
    for (int off = 1; off < 256; off <<= 1) {
        int t = (tid >= off) ? s[tid - off] : 0;
        __syncthreads();
        s[tid] += t;
        __syncthreads();
    }
    int excl = s[tid] - v;
    cur[tid] = excl;
    int node = p * 256 + tid;
    if (node <= N_NODES) offs[node] = beg + excl;
    if (node < N_NODES) dinv[node] = rsqrtf((float)(v + 1));
    __syncthreads();
    for (int i = beg + tid; i < end; i += 256) {
        int pk = bucket[i];
        int slot = atomicAdd(&cur[pk >> 16], 1);
        esrc[beg + slot] = pk & 0xFFFF;
    }
}

// ================= weight transpose+convert =================

__global__ __launch_bounds__(256) void k_wcvt(const float* __restrict__ W,
                                              short* __restrict__ Wt) {
    int idx = blockIdx.x * 256 + threadIdx.x;   // 32768
    int k = idx >> 7;
    int n = idx & 127;
    Wt[n * F_IN + k] = f2bf(W[(size_t)k * HID + n]);
}

__global__ __launch_bounds__(256) void k_wcvt2(const float* __restrict__ W,
                                               short* __restrict__ Wt) {
    int idx = blockIdx.x * 256 + threadIdx.x;   // 4096
    int k = idx >> 5;
    int n = idx & 31;
    Wt[n * HID + k] = f2bf(W[(size_t)k * CLS + n]);
}

// ================= GEMM1 via MFMA: h1[N][128] (bf16) = x @ W1 =================

__global__ __launch_bounds__(256) void k_gemm1_mfma(const float* __restrict__ x,
                                                    const short* __restrict__ Wt,
                                                    short* __restrict__ h) {
    const int lane = threadIdx.x & 63;
    const int w    = threadIdx.x >> 6;
    const int l15  = lane & 15;
    const int lk   = lane >> 4;           // 0..3
    const int row0 = blockIdx.x * 128 + w * 32;

    f32x4 acc[2][8] = {};

#pragma unroll
    for (int ks = 0; ks < F_IN / 32; ++ks) {
        const int kbase = ks * 32 + lk * 8;

        bf16x8 afrag[2];
#pragma unroll
        for (int mt = 0; mt < 2; ++mt) {
            int row = row0 + mt * 16 + l15;
            row = min(row, N_NODES - 1);
            f32x8 xv = *(const f32x8*)(x + (size_t)row * F_IN + kbase);
            bf16x8 a;
#pragma unroll
            for (int e = 0; e < 8; ++e) a[e] = f2bf(xv[e]);
            afrag[mt] = a;
        }

        bf16x8 bfrag[8];
#pragma unroll
        for (int nt = 0; nt < 8; ++nt) {
            int col = nt * 16 + l15;
            bfrag[nt] = *(const bf16x8*)(Wt + (size_t)col * F_IN + kbase);
        }

#pragma unroll
        for (int mt = 0; mt < 2; ++mt)
#pragma unroll
            for (int nt = 0; nt < 8; ++nt)
                acc[mt][nt] = __builtin_amdgcn_mfma_f32_16x16x32_bf16(
                    afrag[mt], bfrag[nt], acc[mt][nt], 0, 0, 0);
    }

#pragma unroll
    for (int mt = 0; mt < 2; ++mt) {
#pragma unroll
        for (int r = 0; r < 4; ++r) {
            int m = row0 + mt * 16 + lk * 4 + r;
            if (m < N_NODES) {
#pragma unroll
                for (int nt = 0; nt < 8; ++nt) {
                    int n = nt * 16 + l15;
                    h[(size_t)m * HID + n] = f2bf(acc[mt][nt][r]);
                }
            }
        }
    }
}

// ================= GEMM2 via MFMA: h2[N][32] (bf16) = relu(a1) @ W2 =================

__global__ __launch_bounds__(256) void k_gemm2_mfma(const short* __restrict__ a,
                                                    const short* __restrict__ Wt,
                                                    short* __restrict__ h) {
    const int lane = threadIdx.x & 63;
    const int w    = threadIdx.x >> 6;
    const int l15  = lane & 15;
    const int lk   = lane >> 4;
    const int row0 = blockIdx.x * 128 + w * 32;

    f32x4 acc[2][2] = {};

#pragma unroll
    for (int ks = 0; ks < HID / 32; ++ks) {
        const int kbase = ks * 32 + lk * 8;

        bf16x8 afrag[2];
#pragma unroll
        for (int mt = 0; mt < 2; ++mt) {
            int row = row0 + mt * 16 + l15;
            row = min(row, N_NODES - 1);
            bf16x8 av = *(const bf16x8*)(a + (size_t)row * HID + kbase);
#pragma unroll
            for (int e = 0; e < 8; ++e) if (av[e] < 0) av[e] = 0;   // bf16 relu via sign bit
            afrag[mt] = av;
        }

        bf16x8 bfrag[2];
#pragma unroll
        for (int nt = 0; nt < 2; ++nt) {
            int col = nt * 16 + l15;
            bfrag[nt] = *(const bf16x8*)(Wt + (size_t)col * HID + kbase);
        }

#pragma unroll
        for (int mt = 0; mt < 2; ++mt)
#pragma unroll
            for (int nt = 0; nt < 2; ++nt)
                acc[mt][nt] = __builtin_amdgcn_mfma_f32_16x16x32_bf16(
                    afrag[mt], bfrag[nt], acc[mt][nt], 0, 0, 0);
    }

#pragma unroll
    for (int mt = 0; mt < 2; ++mt) {
#pragma unroll
        for (int r = 0; r < 4; ++r) {
            int m = row0 + mt * 16 + lk * 4 + r;
            if (m < N_NODES) {
#pragma unroll
                for (int nt = 0; nt < 2; ++nt) {
                    int n = nt * 16 + l15;
                    h[(size_t)m * CLS + n] = f2bf(acc[mt][nt][r]);
                }
            }
        }
    }
}

// ================= gather layer 1 (bf16 in, bf16 out) =================

__global__ __launch_bounds__(256) void k_gather1(const int* __restrict__ offs,
                                                 const int* __restrict__ esrc,
                                                 const short* __restrict__ h,
                                                 const float* __restrict__ dinv,
                                                 const float* __restrict__ b,
                                                 short* __restrict__ out) {
    int node = blockIdx.x * 8 + (threadIdx.x >> 5);
    int lane = threadIdx.x & 31;
    if (node >= N_NODES) return;
    int f = lane * 4;
    float dv = dinv[node];
    s16x4 hv = *(const s16x4*)(h + (size_t)node * HID + f);
    float self = dv * dv;
    float4 acc = { bf2f(hv[0]) * self, bf2f(hv[1]) * self, bf2f(hv[2]) * self, bf2f(hv[3]) * self };
    int beg = offs[node], end = offs[node + 1];
    int p = beg;
    for (; p + 3 < end; p += 4) {
        int s0 = esrc[p + 0], s1 = esrc[p + 1], s2 = esrc[p + 2], s3 = esrc[p + 3];
        float n0 = dinv[s0] * dv, n1 = dinv[s1] * dv, n2 = dinv[s2] * dv, n3 = dinv[s3] * dv;
        s16x4 v0 = *(const s16x4*)(h + (size_t)s0 * HID + f);
        s16x4 v1 = *(const s16x4*)(h + (size_t)s1 * HID + f);
        s16x4 v2 = *(const s16x4*)(h + (size_t)s2 * HID + f);
        s16x4 v3 = *(const s16x4*)(h + (size_t)s3 * HID + f);
        acc.x += bf2f(v0[0]) * n0 + bf2f(v1[0]) * n1 + bf2f(v2[0]) * n2 + bf2f(v3[0]) * n3;
        acc.y += bf2f(v0[1]) * n0 + bf2f(v1[1]) * n1 + bf2f(v2[1]) * n2 + bf2f(v3[1]) * n3;
        acc.z += bf2f(v0[2]) * n0 + bf2f(v1[2]) * n1 + bf2f(v2[2]) * n2 + bf2f(v3[2]) * n3;
        acc.w += bf2f(v0[3]) * n0 + bf2f(v1[3]) * n1 + bf2f(v2[3]) * n2 + bf2f(v3[3]) * n3;
    }
    for (; p < end; ++p) {
        int s = esrc[p];
        float nrm = dinv[s] * dv;
        s16x4 sv = *(const s16x4*)(h + (size_t)s * HID + f);
        acc.x += bf2f(sv[0]) * nrm; acc.y += bf2f(sv[1]) * nrm;
        acc.z += bf2f(sv[2]) * nrm; acc.w += bf2f(sv[3]) * nrm;
    }
    float4 bv = *(const float4*)(b + f);
    s16x4 o = { f2bf(acc.x + bv.x), f2bf(acc.y + bv.y), f2bf(acc.z + bv.z), f2bf(acc.w + bv.w) };
    *(s16x4*)(out + (size_t)node * HID + f) = o;
}

// ================= gather layer 2 + bias + log-softmax =================

__global__ __launch_bounds__(256) void k_gather2(const int* __restrict__ offs,
                                                 const int* __restrict__ esrc,
                                                 const short* __restrict__ h,
                                                 const float* __restrict__ dinv,
                                                 const float* __restrict__ b,
                                                 float* __restrict__ out) {
    int node = blockIdx.x * 32 + (threadIdx.x >> 3);
    int sub = threadIdx.x & 7;
    if (node >= N_NODES) return;
    int f = sub * 4;
    float dv = dinv[node];
    s16x4 hv = *(const s16x4*)(h + (size_t)node * CLS + f);
    float self = dv * dv;
    float4 acc = { bf2f(hv[0]) * self, bf2f(hv[1]) * self, bf2f(hv[2]) * self, bf2f(hv[3]) * self };
    int beg = offs[node], end = offs[node + 1];
    int p = beg;
    for (; p + 1 < end; p += 2) {
        int s0 = esrc[p], s1 = esrc[p + 1];
        float n0 = dinv[s0] * dv, n1 = dinv[s1] * dv;
        s16x4 v0 = *(const s16x4*)(h + (size_t)s0 * CLS + f);
        s16x4 v1 = *(const s16x4*)(h + (size_t)s1 * CLS + f);
        acc.x += bf2f(v0[0]) * n0 + bf2f(v1[0]) * n1;
        acc.y += bf2f(v0[1]) * n0 + bf2f(v1[1]) * n1;
        acc.z += bf2f(v0[2]) * n0 + bf2f(v1[2]) * n1;
        acc.w += bf2f(v0[3]) * n0 + bf2f(v1[3]) * n1;
    }
    if (p < end) {
        int s = esrc[p];
        float nrm = dinv[s] * dv;
        s16x4 sv = *(const s16x4*)(h + (size_t)s * CLS + f);
        acc.x += bf2f(sv[0]) * nrm; acc.y += bf2f(sv[1]) * nrm;
        acc.z += bf2f(sv[2]) * nrm; acc.w += bf2f(sv[3]) * nrm;
    }
    float4 bv = *(const float4*)(b + f);
    acc.x += bv.x; acc.y += bv.y; acc.z += bv.z; acc.w += bv.w;

    float m = fmaxf(fmaxf(acc.x, acc.y), fmaxf(acc.z, acc.w));
    m = fmaxf(m, __shfl_xor(m, 1, 8));
    m = fmaxf(m, __shfl_xor(m, 2, 8));
    m = fmaxf(m, __shfl_xor(m, 4, 8));
    float sum = expf(acc.x - m) + expf(acc.y - m) + expf(acc.z - m) + expf(acc.w - m);
    sum += __shfl_xor(sum, 1, 8);
    sum += __shfl_xor(sum, 2, 8);
    sum += __shfl_xor(sum, 4, 8);
    float l = m + logf(sum);
    float4 o = { acc.x - l, acc.y - l, acc.z - l, acc.w - l };
    *(float4*)(out + (size_t)node * CLS + f) = o;
}

// ================= launch =================

extern "C" void kernel_launch(void* const* d_in, const int* in_sizes, int n_in,
                              void* d_out, int out_size, void* d_ws, size_t ws_size,
                              hipStream_t stream) {
    const float* x  = (const float*)d_in[0];
    const int*   ei = (const int*)d_in[1];
    const float* W1 = (const float*)d_in[2];
    const float* b1 = (const float*)d_in[3];
    const float* W2 = (const float*)d_in[4];
    const float* b2 = (const float*)d_in[5];
    float* out = (float*)d_out;

    const int* src = ei;
    const int* dst = ei + N_EDGE;

    int* counts   = (int*)d_ws;                    // NB*NPART
    int* base     = counts + NB * NPART;           // NB*NPART
    int* partbase = base + NB * NPART;             // 256
    int* bucket   = partbase + 256;                // N_EDGE
    int* offs     = bucket + N_EDGE;               // N_PAD
    int* esrc     = offs + N_PAD;                  // N_EDGE
    float* dinv   = (float*)(esrc + N_EDGE);       // N_PAD
    short* h1     = (short*)(dinv + N_PAD);        // N*HID bf16
    short* a1     = h1 + (size_t)N_NODES * HID;    // N*HID bf16
    short* h2     = a1 + (size_t)N_NODES * HID;    // N*CLS bf16
    short* Wt     = h2 + (size_t)N_NODES * CLS;    // 128*256 bf16
    short* Wt2    = Wt + HID * F_IN;               // 32*128 bf16

    // CSR build (multisplit) + weight converts
    k_histA    <<<NB, 256, 0, stream>>>(dst, counts);
    k_scanA    <<<1,  256, 0, stream>>>(counts, base, partbase);
    k_bucket   <<<NB, 256, 0, stream>>>(src, dst, base, bucket);
    k_csr_final<<<NPART, 256, 0, stream>>>(bucket, partbase, esrc, offs, dinv);
    k_wcvt     <<<128, 256, 0, stream>>>(W1, Wt);
    k_wcvt2    <<<16,  256, 0, stream>>>(W2, Wt2);

    // layer 1
    k_gemm1_mfma<<<391,  256, 0, stream>>>(x, Wt, h1);
    k_gather1   <<<6250, 256, 0, stream>>>(offs, esrc, h1, dinv, b1, a1);

    // layer 2
    k_gemm2_mfma<<<391,  256, 0, stream>>>(a1, Wt2, h2);
    k_gather2   <<<1563, 256, 0, stream>>>(offs, esrc, h2, dinv, b2, out);
}

// Round 6
// 124.959 us; speedup vs baseline: 14.9883x; 1.2351x over previous
//
#include <hip/hip_runtime.h>

#define N_NODES 50000
#define N_PAD   50176      // 196 * 256
#define F_IN 256
#define HID 128
#define CLS 32
#define N_EDGE 800000

#define NB    196          // edge chunks / blocks for multisplit
#define NPART 196          // partitions of 256 nodes
#define CHUNK 4082         // ceil(800000/196)

typedef short bf16x8 __attribute__((ext_vector_type(8)));
typedef short s16x4  __attribute__((ext_vector_type(4)));
typedef float f32x4  __attribute__((ext_vector_type(4)));
typedef float f32x8  __attribute__((ext_vector_type(8)));

static __device__ inline short f2bf(float f) {
    union { float f; unsigned u; } v; v.f = f;
    unsigned r = v.u + 0x7FFFu + ((v.u >> 16) & 1u);
    return (short)(r >> 16);
}

static __device__ inline float bf2f(short b) {
    union { unsigned u; float f; } v;
    v.u = ((unsigned)(unsigned short)b) << 16;
    return v.f;
}

// ================= multisplit CSR build =================

// pass A: per-block coarse histogram (partition = dst>>8)
__global__ __launch_bounds__(256) void k_histA(const int* __restrict__ dst,
                                               int* __restrict__ counts) {
    __shared__ int hist[NPART];
    int tid = threadIdx.x, blk = blockIdx.x;
    if (tid < NPART) hist[tid] = 0;
    __syncthreads();
    int lo = blk * CHUNK, hi = min(lo + CHUNK, N_EDGE);
    for (int e = lo + tid; e < hi; e += 256)
        atomicAdd(&hist[dst[e] >> 8], 1);
    __syncthreads();
    if (tid < NPART) counts[blk * NPART + tid] = hist[tid];
}

// pass B1: per-partition parallel scan over blocks -> local base + partition total
__global__ __launch_bounds__(256) void k_scanP1(const int* __restrict__ counts,
                                                int* __restrict__ base,
                                                int* __restrict__ ptot) {
    __shared__ int s[256];
    int tid = threadIdx.x, p = blockIdx.x;
    int v = (tid < NB) ? counts[tid * NPART + p] : 0;
    s[tid] = v;
    __syncthreads();
#pragma unroll
    for (int off = 1; off < 256; off <<= 1) {
        int t = (tid >= off) ? s[tid - off] : 0;
        __syncthreads();
        s[tid] += t;
        __syncthreads();
    }
    if (tid < NB) base[tid * NPART + p] = s[tid] - v;   // local exclusive
    if (tid == 255) ptot[p] = s[255];
}

// pass B2: single tiny block scans 196 partition totals -> partbase[0..196]
__global__ __launch_bounds__(256) void k_scanP2(const int* __restrict__ ptot,
                                                int* __restrict__ partbase) {
    __shared__ int s[256];
    int tid = threadIdx.x;
    int v = (tid < NPART) ? ptot[tid] : 0;
    s[tid] = v;
    __syncthreads();
#pragma unroll
    for (int off = 1; off < 256; off <<= 1) {
        int t = (tid >= off) ? s[tid - off] : 0;
        __syncthreads();
        s[tid] += t;
        __syncthreads();
    }
    if (tid <= NPART) partbase[tid] = s[tid] - v;
}

// pass B3: base[b][p] += partbase[p]
__global__ __launch_bounds__(256) void k_scanP3(int* __restrict__ base,
                                                const int* __restrict__ partbase) {
    int i = blockIdx.x * 256 + threadIdx.x;
    if (i < NB * NPART) base[i] += partbase[i % NPART];
}

// pass C: bucket edges into private runs, packed (d8<<16)|src
__global__ __launch_bounds__(256) void k_bucket(const int* __restrict__ src,
                                                const int* __restrict__ dst,
                                                const int* __restrict__ base,
                                                int* __restrict__ bucket) {
    __shared__ int cur[NPART];
    int tid = threadIdx.x, blk = blockIdx.x;
    if (tid < NPART) cur[tid] = base[blk * NPART + tid];
    __syncthreads();
    int lo = blk * CHUNK, hi = min(lo + CHUNK, N_EDGE);
    for (int e = lo + tid; e < hi; e += 256) {
        int d = dst[e], s = src[e];
        int pos = atomicAdd(&cur[d >> 8], 1);
        bucket[pos] = ((d & 255) << 16) | s;
    }
}

// pass D: per-partition 256-bin sort; emit esrc, offs, dinv
__global__ __launch_bounds__(256) void k_csr_final(const int* __restrict__ bucket,
                                                   const int* __restrict__ partbase,
                                                   int* __restrict__ esrc,
                                                   int* __restrict__ offs,
                                                   float* __restrict__ dinv) {
    __shared__ int hist[256], s[256], cur[256];
    int tid = threadIdx.x, p = blockIdx.x;
    int beg = partbase[p], end = partbase[p + 1];
    hist[tid] = 0;
    __syncthreads();
    for (int i = beg + tid; i < end; i += 256)
        atomicAdd(&hist[bucket[i] >> 16], 1);
    __syncthreads();
    int v = hist[tid];
    s[tid] = v;
    __syncthreads();
#pragma unroll
    for (int off = 1; off < 256; off <<= 1) {
        int t = (tid >= off) ? s[tid - off] : 0;
        __syncthreads();
        s[tid] += t;
        __syncthreads();
    }
    int excl = s[tid] - v;
    cur[tid] = excl;
    int node = p * 256 + tid;
    if (node <= N_NODES) offs[node] = beg + excl;
    if (node < N_NODES) dinv[node] = rsqrtf((float)(v + 1));
    __syncthreads();
    for (int i = beg + tid; i < end; i += 256) {
        int pk = bucket[i];
        int slot = atomicAdd(&cur[pk >> 16], 1);
        esrc[beg + slot] = pk & 0xFFFF;
    }
}

// ================= weight transpose+convert =================

__global__ __launch_bounds__(256) void k_wcvt(const float* __restrict__ W,
                                              short* __restrict__ Wt) {
    int idx = blockIdx.x * 256 + threadIdx.x;   // 32768
    int k = idx >> 7;
    int n = idx & 127;
    Wt[n * F_IN + k] = f2bf(W[(size_t)k * HID + n]);
}

__global__ __launch_bounds__(256) void k_wcvt2(const float* __restrict__ W,
                                               short* __restrict__ Wt) {
    int idx = blockIdx.x * 256 + threadIdx.x;   // 4096
    int k = idx >> 5;
    int n = idx & 31;
    Wt[n * HID + k] = f2bf(W[(size_t)k * CLS + n]);
}

// ================= GEMM1 via MFMA: h1[N][128] (bf16) = x @ W1 =================

__global__ __launch_bounds__(256) void k_gemm1_mfma(const float* __restrict__ x,
                                                    const short* __restrict__ Wt,
                                                    short* __restrict__ h) {
    const int lane = threadIdx.x & 63;
    const int w    = threadIdx.x >> 6;
    const int l15  = lane & 15;
    const int lk   = lane >> 4;           // 0..3
    const int row0 = blockIdx.x * 128 + w * 32;

    f32x4 acc[2][8] = {};

#pragma unroll
    for (int ks = 0; ks < F_IN / 32; ++ks) {
        const int kbase = ks * 32 + lk * 8;

        bf16x8 afrag[2];
#pragma unroll
        for (int mt = 0; mt < 2; ++mt) {
            int row = row0 + mt * 16 + l15;
            row = min(row, N_NODES - 1);
            f32x8 xv = *(const f32x8*)(x + (size_t)row * F_IN + kbase);
            bf16x8 a;
#pragma unroll
            for (int e = 0; e < 8; ++e) a[e] = f2bf(xv[e]);
            afrag[mt] = a;
        }

        bf16x8 bfrag[8];
#pragma unroll
        for (int nt = 0; nt < 8; ++nt) {
            int col = nt * 16 + l15;
            bfrag[nt] = *(const bf16x8*)(Wt + (size_t)col * F_IN + kbase);
        }

#pragma unroll
        for (int mt = 0; mt < 2; ++mt)
#pragma unroll
            for (int nt = 0; nt < 8; ++nt)
                acc[mt][nt] = __builtin_amdgcn_mfma_f32_16x16x32_bf16(
                    afrag[mt], bfrag[nt], acc[mt][nt], 0, 0, 0);
    }

#pragma unroll
    for (int mt = 0; mt < 2; ++mt) {
#pragma unroll
        for (int r = 0; r < 4; ++r) {
            int m = row0 + mt * 16 + lk * 4 + r;
            if (m < N_NODES) {
#pragma unroll
                for (int nt = 0; nt < 8; ++nt) {
                    int n = nt * 16 + l15;
                    h[(size_t)m * HID + n] = f2bf(acc[mt][nt][r]);
                }
            }
        }
    }
}

// ================= GEMM2 via MFMA: h2[N][32] (bf16) = relu(a1) @ W2 =================

__global__ __launch_bounds__(256) void k_gemm2_mfma(const short* __restrict__ a,
                                                    const short* __restrict__ Wt,
                                                    short* __restrict__ h) {
    const int lane = threadIdx.x & 63;
    const int w    = threadIdx.x >> 6;
    const int l15  = lane & 15;
    const int lk   = lane >> 4;
    const int row0 = blockIdx.x * 128 + w * 32;

    f32x4 acc[2][2] = {};

#pragma unroll
    for (int ks = 0; ks < HID / 32; ++ks) {
        const int kbase = ks * 32 + lk * 8;

        bf16x8 afrag[2];
#pragma unroll
        for (int mt = 0; mt < 2; ++mt) {
            int row = row0 + mt * 16 + l15;
            row = min(row, N_NODES - 1);
            bf16x8 av = *(const bf16x8*)(a + (size_t)row * HID + kbase);
#pragma unroll
            for (int e = 0; e < 8; ++e) if (av[e] < 0) av[e] = 0;   // bf16 relu via sign bit
            afrag[mt] = av;
        }

        bf16x8 bfrag[2];
#pragma unroll
        for (int nt = 0; nt < 2; ++nt) {
            int col = nt * 16 + l15;
            bfrag[nt] = *(const bf16x8*)(Wt + (size_t)col * HID + kbase);
        }

#pragma unroll
        for (int mt = 0; mt < 2; ++mt)
#pragma unroll
            for (int nt = 0; nt < 2; ++nt)
                acc[mt][nt] = __builtin_amdgcn_mfma_f32_16x16x32_bf16(
                    afrag[mt], bfrag[nt], acc[mt][nt], 0, 0, 0);
    }

#pragma unroll
    for (int mt = 0; mt < 2; ++mt) {
#pragma unroll
        for (int r = 0; r < 4; ++r) {
            int m = row0 + mt * 16 + lk * 4 + r;
            if (m < N_NODES) {
#pragma unroll
                for (int nt = 0; nt < 2; ++nt) {
                    int n = nt * 16 + l15;
                    h[(size_t)m * CLS + n] = f2bf(acc[mt][nt][r]);
                }
            }
        }
    }
}

// ================= gather layer 1 (bf16 in, bf16 out) =================

__global__ __launch_bounds__(256) void k_gather1(const int* __restrict__ offs,
                                                 const int* __restrict__ esrc,
                                                 const short* __restrict__ h,
                                                 const float* __restrict__ dinv,
                                                 const float* __restrict__ b,
                                                 short* __restrict__ out) {
    int node = blockIdx.x * 8 + (threadIdx.x >> 5);
    int lane = threadIdx.x & 31;
    if (node >= N_NODES) return;
    int f = lane * 4;
    float dv = dinv[node];
    s16x4 hv = *(const s16x4*)(h + (size_t)node * HID + f);
    float self = dv * dv;
    float4 acc = { bf2f(hv[0]) * self, bf2f(hv[1]) * self, bf2f(hv[2]) * self, bf2f(hv[3]) * self };
    int beg = offs[node], end = offs[node + 1];
    int p = beg;
    for (; p + 3 < end; p += 4) {
        int s0 = esrc[p + 0], s1 = esrc[p + 1], s2 = esrc[p + 2], s3 = esrc[p + 3];
        float n0 = dinv[s0] * dv, n1 = dinv[s1] * dv, n2 = dinv[s2] * dv, n3 = dinv[s3] * dv;
        s16x4 v0 = *(const s16x4*)(h + (size_t)s0 * HID + f);
        s16x4 v1 = *(const s16x4*)(h + (size_t)s1 * HID + f);
        s16x4 v2 = *(const s16x4*)(h + (size_t)s2 * HID + f);
        s16x4 v3 = *(const s16x4*)(h + (size_t)s3 * HID + f);
        acc.x += bf2f(v0[0]) * n0 + bf2f(v1[0]) * n1 + bf2f(v2[0]) * n2 + bf2f(v3[0]) * n3;
        acc.y += bf2f(v0[1]) * n0 + bf2f(v1[1]) * n1 + bf2f(v2[1]) * n2 + bf2f(v3[1]) * n3;
        acc.z += bf2f(v0[2]) * n0 + bf2f(v1[2]) * n1 + bf2f(v2[2]) * n2 + bf2f(v3[2]) * n3;
        acc.w += bf2f(v0[3]) * n0 + bf2f(v1[3]) * n1 + bf2f(v2[3]) * n2 + bf2f(v3[3]) * n3;
    }
    for (; p < end; ++p) {
        int s = esrc[p];
        float nrm = dinv[s] * dv;
        s16x4 sv = *(const s16x4*)(h + (size_t)s * HID + f);
        acc.x += bf2f(sv[0]) * nrm; acc.y += bf2f(sv[1]) * nrm;
        acc.z += bf2f(sv[2]) * nrm; acc.w += bf2f(sv[3]) * nrm;
    }
    float4 bv = *(const float4*)(b + f);
    s16x4 o = { f2bf(acc.x + bv.x), f2bf(acc.y + bv.y), f2bf(acc.z + bv.z), f2bf(acc.w + bv.w) };
    *(s16x4*)(out + (size_t)node * HID + f) = o;
}

// ================= gather layer 2 + bias + log-softmax =================

__global__ __launch_bounds__(256) void k_gather2(const int* __restrict__ offs,
                                                 const int* __restrict__ esrc,
                                                 const short* __restrict__ h,
                                                 const float* __restrict__ dinv,
                                                 const float* __restrict__ b,
                                                 float* __restrict__ out) {
    int node = blockIdx.x * 32 + (threadIdx.x >> 3);
    int sub = threadIdx.x & 7;
    if (node >= N_NODES) return;
    int f = sub * 4;
    float dv = dinv[node];
    s16x4 hv = *(const s16x4*)(h + (size_t)node * CLS + f);
    float self = dv * dv;
    float4 acc = { bf2f(hv[0]) * self, bf2f(hv[1]) * self, bf2f(hv[2]) * self, bf2f(hv[3]) * self };
    int beg = offs[node], end = offs[node + 1];
    int p = beg;
    for (; p + 1 < end; p += 2) {
        int s0 = esrc[p], s1 = esrc[p + 1];
        float n0 = dinv[s0] * dv, n1 = dinv[s1] * dv;
        s16x4 v0 = *(const s16x4*)(h + (size_t)s0 * CLS + f);
        s16x4 v1 = *(const s16x4*)(h + (size_t)s1 * CLS + f);
        acc.x += bf2f(v0[0]) * n0 + bf2f(v1[0]) * n1;
        acc.y += bf2f(v0[1]) * n0 + bf2f(v1[1]) * n1;
        acc.z += bf2f(v0[2]) * n0 + bf2f(v1[2]) * n1;
        acc.w += bf2f(v0[3]) * n0 + bf2f(v1[3]) * n1;
    }
    if (p < end) {
        int s = esrc[p];
        float nrm = dinv[s] * dv;
        s16x4 sv = *(const s16x4*)(h + (size_t)s * CLS + f);
        acc.x += bf2f(sv[0]) * nrm; acc.y += bf2f(sv[1]) * nrm;
        acc.z += bf2f(sv[2]) * nrm; acc.w += bf2f(sv[3]) * nrm;
    }
    float4 bv = *(const float4*)(b + f);
    acc.x += bv.x; acc.y += bv.y; acc.z += bv.z; acc.w += bv.w;

    float m = fmaxf(fmaxf(acc.x, acc.y), fmaxf(acc.z, acc.w));
    m = fmaxf(m, __shfl_xor(m, 1, 8));
    m = fmaxf(m, __shfl_xor(m, 2, 8));
    m = fmaxf(m, __shfl_xor(m, 4, 8));
    float sum = expf(acc.x - m) + expf(acc.y - m) + expf(acc.z - m) + expf(acc.w - m);
    sum += __shfl_xor(sum, 1, 8);
    sum += __shfl_xor(sum, 2, 8);
    sum += __shfl_xor(sum, 4, 8);
    float l = m + logf(sum);
    float4 o = { acc.x - l, acc.y - l, acc.z - l, acc.w - l };
    *(float4*)(out + (size_t)node * CLS + f) = o;
}

// ================= launch =================

extern "C" void kernel_launch(void* const* d_in, const int* in_sizes, int n_in,
                              void* d_out, int out_size, void* d_ws, size_t ws_size,
                              hipStream_t stream) {
    const float* x  = (const float*)d_in[0];
    const int*   ei = (const int*)d_in[1];
    const float* W1 = (const float*)d_in[2];
    const float* b1 = (const float*)d_in[3];
    const float* W2 = (const float*)d_in[4];
    const float* b2 = (const float*)d_in[5];
    float* out = (float*)d_out;

    const int* src = ei;
    const int* dst = ei + N_EDGE;

    int* counts   = (int*)d_ws;                    // NB*NPART
    int* base     = counts + NB * NPART;           // NB*NPART
    int* ptot     = base + NB * NPART;             // 256
    int* partbase = ptot + 256;                    // 256
    int* bucket   = partbase + 256;                // N_EDGE
    int* offs     = bucket + N_EDGE;               // N_PAD
    int* esrc     = offs + N_PAD;                  // N_EDGE
    float* dinv   = (float*)(esrc + N_EDGE);       // N_PAD
    short* h1     = (short*)(dinv + N_PAD);        // N*HID bf16
    short* a1     = h1 + (size_t)N_NODES * HID;    // N*HID bf16
    short* h2     = a1 + (size_t)N_NODES * HID;    // N*CLS bf16
    short* Wt     = h2 + (size_t)N_NODES * CLS;    // 128*256 bf16
    short* Wt2    = Wt + HID * F_IN;               // 32*128 bf16

    // CSR build (multisplit, parallel scan) + weight converts
    k_histA    <<<NB,    256, 0, stream>>>(dst, counts);
    k_scanP1   <<<NPART, 256, 0, stream>>>(counts, base, ptot);
    k_scanP2   <<<1,     256, 0, stream>>>(ptot, partbase);
    k_scanP3   <<<151,   256, 0, stream>>>(base, partbase);
    k_bucket   <<<NB,    256, 0, stream>>>(src, dst, base, bucket);
    k_csr_final<<<NPART, 256, 0, stream>>>(bucket, partbase, esrc, offs, dinv);
    k_wcvt     <<<128,   256, 0, stream>>>(W1, Wt);
    k_wcvt2    <<<16,    256, 0, stream>>>(W2, Wt2);

    // layer 1
    k_gemm1_mfma<<<391,  256, 0, stream>>>(x, Wt, h1);
    k_gather1   <<<6250, 256, 0, stream>>>(offs, esrc, h1, dinv, b1, a1);

    // layer 2
    k_gemm2_mfma<<<391,  256, 0, stream>>>(a1, Wt2, h2);
    k_gather2   <<<1563, 256, 0, stream>>>(offs, esrc, h2, dinv, b2, out);
}

// Round 7
// 107.728 us; speedup vs baseline: 17.3855x; 1.1599x over previous
//
#include <hip/hip_runtime.h>

#define N_NODES 50000
#define N_PAD   50176      // 196 * 256
#define F_IN 256
#define HID 128
#define CLS 32
#define N_EDGE 800000

#define NB    196          // edge chunks / blocks for multisplit
#define NPART 196          // partitions of 256 nodes
#define CHUNK 4082         // ceil(800000/196)

typedef short bf16x8 __attribute__((ext_vector_type(8)));
typedef short s16x4  __attribute__((ext_vector_type(4)));
typedef float f32x2  __attribute__((ext_vector_type(2)));
typedef float f32x4  __attribute__((ext_vector_type(4)));
typedef float f32x8  __attribute__((ext_vector_type(8)));

static __device__ inline short f2bf(float f) {
    union { float f; unsigned u; } v; v.f = f;
    unsigned r = v.u + 0x7FFFu + ((v.u >> 16) & 1u);
    return (short)(r >> 16);
}

static __device__ inline float bf2f(short b) {
    union { unsigned u; float f; } v;
    v.u = ((unsigned)(unsigned short)b) << 16;
    return v.f;
}

static __device__ inline unsigned char f2fp8(float f) {
    return (unsigned char)(__builtin_amdgcn_cvt_pk_fp8_f32(f, f, 0, false) & 0xFF);
}

// ================= multisplit CSR build =================

__global__ __launch_bounds__(256) void k_histA(const int* __restrict__ dst,
                                               int* __restrict__ counts) {
    __shared__ int hist[NPART];
    int tid = threadIdx.x, blk = blockIdx.x;
    if (tid < NPART) hist[tid] = 0;
    __syncthreads();
    int lo = blk * CHUNK, hi = min(lo + CHUNK, N_EDGE);
    for (int e = lo + tid; e < hi; e += 256)
        atomicAdd(&hist[dst[e] >> 8], 1);
    __syncthreads();
    if (tid < NPART) counts[blk * NPART + tid] = hist[tid];
}

// per-partition parallel scan over blocks -> local base + partition total
__global__ __launch_bounds__(256) void k_scanP1(const int* __restrict__ counts,
                                                int* __restrict__ base,
                                                int* __restrict__ ptot) {
    __shared__ int s[256];
    int tid = threadIdx.x, p = blockIdx.x;
    int v = (tid < NB) ? counts[tid * NPART + p] : 0;
    s[tid] = v;
    __syncthreads();
#pragma unroll
    for (int off = 1; off < 256; off <<= 1) {
        int t = (tid >= off) ? s[tid - off] : 0;
        __syncthreads();
        s[tid] += t;
        __syncthreads();
    }
    if (tid < NB) base[tid * NPART + p] = s[tid] - v;   // local exclusive
    if (tid == 255) ptot[p] = s[255];
}

// merged: block 0 = scan of partition totals; blocks 1..128 = W1 cvt; 129..144 = W2 cvt
__global__ __launch_bounds__(256) void k_misc(const int* __restrict__ ptot,
                                              int* __restrict__ partbase,
                                              const float* __restrict__ W1,
                                              short* __restrict__ Wt,
                                              const float* __restrict__ W2,
                                              short* __restrict__ Wt2) {
    int blk = blockIdx.x, tid = threadIdx.x;
    if (blk == 0) {
        __shared__ int s[256];
        int v = (tid < NPART) ? ptot[tid] : 0;
        s[tid] = v;
        __syncthreads();
#pragma unroll
        for (int off = 1; off < 256; off <<= 1) {
            int t = (tid >= off) ? s[tid - off] : 0;
            __syncthreads();
            s[tid] += t;
            __syncthreads();
        }
        if (tid <= NPART) partbase[tid] = s[tid] - v;
    } else if (blk <= 128) {
        int idx = (blk - 1) * 256 + tid;        // 32768
        int k = idx >> 7;
        int n = idx & 127;
        Wt[n * F_IN + k] = f2bf(W1[(size_t)k * HID + n]);
    } else {
        int idx = (blk - 129) * 256 + tid;      // 4096
        int k = idx >> 5;
        int n = idx & 31;
        Wt2[n * HID + k] = f2bf(W2[(size_t)k * CLS + n]);
    }
}

// bucket edges into private runs, packed (d8<<16)|src ; adds partbase here (scanP3 folded in)
__global__ __launch_bounds__(256) void k_bucket(const int* __restrict__ src,
                                                const int* __restrict__ dst,
                                                const int* __restrict__ base,
                                                const int* __restrict__ partbase,
                                                int* __restrict__ bucket) {
    __shared__ int cur[NPART];
    int tid = threadIdx.x, blk = blockIdx.x;
    if (tid < NPART) cur[tid] = base[blk * NPART + tid] + partbase[tid];
    __syncthreads();
    int lo = blk * CHUNK, hi = min(lo + CHUNK, N_EDGE);
    for (int e = lo + tid; e < hi; e += 256) {
        int d = dst[e], s = src[e];
        int pos = atomicAdd(&cur[d >> 8], 1);
        bucket[pos] = ((d & 255) << 16) | s;
    }
}

// per-partition 256-bin sort; emit esrc, offs, dinv
__global__ __launch_bounds__(256) void k_csr_final(const int* __restrict__ bucket,
                                                   const int* __restrict__ partbase,
                                                   int* __restrict__ esrc,
                                                   int* __restrict__ offs,
                                                   float* __restrict__ dinv) {
    __shared__ int hist[256], s[256], cur[256];
    int tid = threadIdx.x, p = blockIdx.x;
    int beg = partbase[p], end = partbase[p + 1];
    hist[tid] = 0;
    __syncthreads();
    for (int i = beg + tid; i < end; i += 256)
        atomicAdd(&hist[bucket[i] >> 16], 1);
    __syncthreads();
    int v = hist[tid];
    s[tid] = v;
    __syncthreads();
#pragma unroll
    for (int off = 1; off < 256; off <<= 1) {
        int t = (tid >= off) ? s[tid - off] : 0;
        __syncthreads();
        s[tid] += t;
        __syncthreads();
    }
    int excl = s[tid] - v;
    cur[tid] = excl;
    int node = p * 256 + tid;
    if (node <= N_NODES) offs[node] = beg + excl;
    if (node < N_NODES) dinv[node] = rsqrtf((float)(v + 1));
    __syncthreads();
    for (int i = beg + tid; i < end; i += 256) {
        int pk = bucket[i];
        int slot = atomicAdd(&cur[pk >> 16], 1);
        esrc[beg + slot] = pk & 0xFFFF;
    }
}

// ================= GEMM1 via MFMA: h1[N][128] (fp8) = x @ W1 =================

__global__ __launch_bounds__(256) void k_gemm1_mfma(const float* __restrict__ x,
                                                    const short* __restrict__ Wt,
                                                    unsigned char* __restrict__ h) {
    const int lane = threadIdx.x & 63;
    const int w    = threadIdx.x >> 6;
    const int l15  = lane & 15;
    const int lk   = lane >> 4;           // 0..3
    const int row0 = blockIdx.x * 128 + w * 32;

    f32x4 acc[2][8] = {};

#pragma unroll
    for (int ks = 0; ks < F_IN / 32; ++ks) {
        const int kbase = ks * 32 + lk * 8;

        bf16x8 afrag[2];
#pragma unroll
        for (int mt = 0; mt < 2; ++mt) {
            int row = row0 + mt * 16 + l15;
            row = min(row, N_NODES - 1);
            f32x8 xv = *(const f32x8*)(x + (size_t)row * F_IN + kbase);
            bf16x8 a;
#pragma unroll
            for (int e = 0; e < 8; ++e) a[e] = f2bf(xv[e]);
            afrag[mt] = a;
        }

        bf16x8 bfrag[8];
#pragma unroll
        for (int nt = 0; nt < 8; ++nt) {
            int col = nt * 16 + l15;
            bfrag[nt] = *(const bf16x8*)(Wt + (size_t)col * F_IN + kbase);
        }

#pragma unroll
        for (int mt = 0; mt < 2; ++mt)
#pragma unroll
            for (int nt = 0; nt < 8; ++nt)
                acc[mt][nt] = __builtin_amdgcn_mfma_f32_16x16x32_bf16(
                    afrag[mt], bfrag[nt], acc[mt][nt], 0, 0, 0);
    }

#pragma unroll
    for (int mt = 0; mt < 2; ++mt) {
#pragma unroll
        for (int r = 0; r < 4; ++r) {
            int m = row0 + mt * 16 + lk * 4 + r;
            if (m < N_NODES) {
#pragma unroll
                for (int nt = 0; nt < 8; ++nt) {
                    int n = nt * 16 + l15;
                    h[(size_t)m * HID + n] = f2fp8(acc[mt][nt][r]);
                }
            }
        }
    }
}

// ================= GEMM2 via MFMA: h2[N][32] (bf16) = relu(a1) @ W2 =================

__global__ __launch_bounds__(256) void k_gemm2_mfma(const short* __restrict__ a,
                                                    const short* __restrict__ Wt,
                                                    short* __restrict__ h) {
    const int lane = threadIdx.x & 63;
    const int w    = threadIdx.x >> 6;
    const int l15  = lane & 15;
    const int lk   = lane >> 4;
    const int row0 = blockIdx.x * 128 + w * 32;

    f32x4 acc[2][2] = {};

#pragma unroll
    for (int ks = 0; ks < HID / 32; ++ks) {
        const int kbase = ks * 32 + lk * 8;

        bf16x8 afrag[2];
#pragma unroll
        for (int mt = 0; mt < 2; ++mt) {
            int row = row0 + mt * 16 + l15;
            row = min(row, N_NODES - 1);
            bf16x8 av = *(const bf16x8*)(a + (size_t)row * HID + kbase);
#pragma unroll
            for (int e = 0; e < 8; ++e) if (av[e] < 0) av[e] = 0;   // bf16 relu via sign bit
            afrag[mt] = av;
        }

        bf16x8 bfrag[2];
#pragma unroll
        for (int nt = 0; nt < 2; ++nt) {
            int col = nt * 16 + l15;
            bfrag[nt] = *(const bf16x8*)(Wt + (size_t)col * HID + kbase);
        }

#pragma unroll
        for (int mt = 0; mt < 2; ++mt)
#pragma unroll
            for (int nt = 0; nt < 2; ++nt)
                acc[mt][nt] = __builtin_amdgcn_mfma_f32_16x16x32_bf16(
                    afrag[mt], bfrag[nt], acc[mt][nt], 0, 0, 0);
    }

#pragma unroll
    for (int mt = 0; mt < 2; ++mt) {
#pragma unroll
        for (int r = 0; r < 4; ++r) {
            int m = row0 + mt * 16 + lk * 4 + r;
            if (m < N_NODES) {
#pragma unroll
                for (int nt = 0; nt < 2; ++nt) {
                    int n = nt * 16 + l15;
                    h[(size_t)m * CLS + n] = f2bf(acc[mt][nt][r]);
                }
            }
        }
    }
}

// ================= gather layer 1 (fp8 in, bf16 out) =================

__global__ __launch_bounds__(256) void k_gather1(const int* __restrict__ offs,
                                                 const int* __restrict__ esrc,
                                                 const unsigned char* __restrict__ h,
                                                 const float* __restrict__ dinv,
                                                 const float* __restrict__ b,
                                                 short* __restrict__ out) {
    int node = blockIdx.x * 8 + (threadIdx.x >> 5);
    int lane = threadIdx.x & 31;
    if (node >= N_NODES) return;
    int f = lane * 4;
    float dv = dinv[node];
    unsigned hv = *(const unsigned*)(h + (size_t)node * HID + f);
    f32x2 hlo = __builtin_amdgcn_cvt_pk_f32_fp8(hv, false);
    f32x2 hhi = __builtin_amdgcn_cvt_pk_f32_fp8(hv, true);
    float self = dv * dv;
    float4 acc = { hlo[0] * self, hlo[1] * self, hhi[0] * self, hhi[1] * self };
    int beg = offs[node], end = offs[node + 1];
    int p = beg;
    for (; p + 3 < end; p += 4) {
        int s0 = esrc[p + 0], s1 = esrc[p + 1], s2 = esrc[p + 2], s3 = esrc[p + 3];
        float n0 = dinv[s0] * dv, n1 = dinv[s1] * dv, n2 = dinv[s2] * dv, n3 = dinv[s3] * dv;
        unsigned v0 = *(const unsigned*)(h + (size_t)s0 * HID + f);
        unsigned v1 = *(const unsigned*)(h + (size_t)s1 * HID + f);
        unsigned v2 = *(const unsigned*)(h + (size_t)s2 * HID + f);
        unsigned v3 = *(const unsigned*)(h + (size_t)s3 * HID + f);
        f32x2 l0 = __builtin_amdgcn_cvt_pk_f32_fp8(v0, false), u0 = __builtin_amdgcn_cvt_pk_f32_fp8(v0, true);
        f32x2 l1 = __builtin_amdgcn_cvt_pk_f32_fp8(v1, false), u1 = __builtin_amdgcn_cvt_pk_f32_fp8(v1, true);
        f32x2 l2 = __builtin_amdgcn_cvt_pk_f32_fp8(v2, false), u2 = __builtin_amdgcn_cvt_pk_f32_fp8(v2, true);
        f32x2 l3 = __builtin_amdgcn_cvt_pk_f32_fp8(v3, false), u3 = __builtin_amdgcn_cvt_pk_f32_fp8(v3, true);
        acc.x += l0[0] * n0 + l1[0] * n1 + l2[0] * n2 + l3[0] * n3;
        acc.y += l0[1] * n0 + l1[1] * n1 + l2[1] * n2 + l3[1] * n3;
        acc.z += u0[0] * n0 + u1[0] * n1 + u2[0] * n2 + u3[0] * n3;
        acc.w += u0[1] * n0 + u1[1] * n1 + u2[1] * n2 + u3[1] * n3;
    }
    for (; p < end; ++p) {
        int s = esrc[p];
        float nrm = dinv[s] * dv;
        unsigned v = *(const unsigned*)(h + (size_t)s * HID + f);
        f32x2 l = __builtin_amdgcn_cvt_pk_f32_fp8(v, false), u = __builtin_amdgcn_cvt_pk_f32_fp8(v, true);
        acc.x += l[0] * nrm; acc.y += l[1] * nrm;
        acc.z += u[0] * nrm; acc.w += u[1] * nrm;
    }
    float4 bv = *(const float4*)(b + f);
    s16x4 o = { f2bf(acc.x + bv.x), f2bf(acc.y + bv.y), f2bf(acc.z + bv.z), f2bf(acc.w + bv.w) };
    *(s16x4*)(out + (size_t)node * HID + f) = o;
}

// ================= gather layer 2 + bias + log-softmax =================

__global__ __launch_bounds__(256) void k_gather2(const int* __restrict__ offs,
                                                 const int* __restrict__ esrc,
                                                 const short* __restrict__ h,
                                                 const float* __restrict__ dinv,
                                                 const float* __restrict__ b,
                                                 float* __restrict__ out) {
    int node = blockIdx.x * 32 + (threadIdx.x >> 3);
    int sub = threadIdx.x & 7;
    if (node >= N_NODES) return;
    int f = sub * 4;
    float dv = dinv[node];
    s16x4 hv = *(const s16x4*)(h + (size_t)node * CLS + f);
    float self = dv * dv;
    float4 acc = { bf2f(hv[0]) * self, bf2f(hv[1]) * self, bf2f(hv[2]) * self, bf2f(hv[3]) * self };
    int beg = offs[node], end = offs[node + 1];
    int p = beg;
    for (; p + 3 < end; p += 4) {
        int s0 = esrc[p], s1 = esrc[p + 1], s2 = esrc[p + 2], s3 = esrc[p + 3];
        float n0 = dinv[s0] * dv, n1 = dinv[s1] * dv, n2 = dinv[s2] * dv, n3 = dinv[s3] * dv;
        s16x4 v0 = *(const s16x4*)(h + (size_t)s0 * CLS + f);
        s16x4 v1 = *(const s16x4*)(h + (size_t)s1 * CLS + f);
        s16x4 v2 = *(const s16x4*)(h + (size_t)s2 * CLS + f);
        s16x4 v3 = *(const s16x4*)(h + (size_t)s3 * CLS + f);
        acc.x += bf2f(v0[0]) * n0 + bf2f(v1[0]) * n1 + bf2f(v2[0]) * n2 + bf2f(v3[0]) * n3;
        acc.y += bf2f(v0[1]) * n0 + bf2f(v1[1]) * n1 + bf2f(v2[1]) * n2 + bf2f(v3[1]) * n3;
        acc.z += bf2f(v0[2]) * n0 + bf2f(v1[2]) * n1 + bf2f(v2[2]) * n2 + bf2f(v3[2]) * n3;
        acc.w += bf2f(v0[3]) * n0 + bf2f(v1[3]) * n1 + bf2f(v2[3]) * n2 + bf2f(v3[3]) * n3;
    }
    for (; p < end; ++p) {
        int s = esrc[p];
        float nrm = dinv[s] * dv;
        s16x4 sv = *(const s16x4*)(h + (size_t)s * CLS + f);
        acc.x += bf2f(sv[0]) * nrm; acc.y += bf2f(sv[1]) * nrm;
        acc.z += bf2f(sv[2]) * nrm; acc.w += bf2f(sv[3]) * nrm;
    }
    float4 bv = *(const float4*)(b + f);
    acc.x += bv.x; acc.y += bv.y; acc.z += bv.z; acc.w += bv.w;

    float m = fmaxf(fmaxf(acc.x, acc.y), fmaxf(acc.z, acc.w));
    m = fmaxf(m, __shfl_xor(m, 1, 8));
    m = fmaxf(m, __shfl_xor(m, 2, 8));
    m = fmaxf(m, __shfl_xor(m, 4, 8));
    float sum = expf(acc.x - m) + expf(acc.y - m) + expf(acc.z - m) + expf(acc.w - m);
    sum += __shfl_xor(sum, 1, 8);
    sum += __shfl_xor(sum, 2, 8);
    sum += __shfl_xor(sum, 4, 8);
    float l = m + logf(sum);
    float4 o = { acc.x - l, acc.y - l, acc.z - l, acc.w - l };
    *(float4*)(out + (size_t)node * CLS + f) = o;
}

// ================= launch =================

extern "C" void kernel_launch(void* const* d_in, const int* in_sizes, int n_in,
                              void* d_out, int out_size, void* d_ws, size_t ws_size,
                              hipStream_t stream) {
    const float* x  = (const float*)d_in[0];
    const int*   ei = (const int*)d_in[1];
    const float* W1 = (const float*)d_in[2];
    const float* b1 = (const float*)d_in[3];
    const float* W2 = (const float*)d_in[4];
    const float* b2 = (const float*)d_in[5];
    float* out = (float*)d_out;

    const int* src = ei;
    const int* dst = ei + N_EDGE;

    int* counts   = (int*)d_ws;                           // NB*NPART
    int* base     = counts + NB * NPART;                  // NB*NPART
    int* ptot     = base + NB * NPART;                    // 256
    int* partbase = ptot + 256;                           // 256
    int* bucket   = partbase + 256;                       // N_EDGE
    int* offs     = bucket + N_EDGE;                      // N_PAD
    int* esrc     = offs + N_PAD;                         // N_EDGE
    float* dinv   = (float*)(esrc + N_EDGE);              // N_PAD
    unsigned char* h1 = (unsigned char*)(dinv + N_PAD);   // N*HID fp8
    short* a1     = (short*)(h1 + (size_t)N_NODES * HID); // N*HID bf16
    short* h2     = a1 + (size_t)N_NODES * HID;           // N*CLS bf16
    short* Wt     = h2 + (size_t)N_NODES * CLS;           // 128*256 bf16
    short* Wt2    = Wt + HID * F_IN;                      // 32*128 bf16

    // CSR build (multisplit, parallel scan) + weight converts
    k_histA    <<<NB,    256, 0, stream>>>(dst, counts);
    k_scanP1   <<<NPART, 256, 0, stream>>>(counts, base, ptot);
    k_misc     <<<145,   256, 0, stream>>>(ptot, partbase, W1, Wt, W2, Wt2);
    k_bucket   <<<NB,    256, 0, stream>>>(src, dst, base, partbase, bucket);
    k_csr_final<<<NPART, 256, 0, stream>>>(bucket, partbase, esrc, offs, dinv);

    // layer 1
    k_gemm1_mfma<<<391,  256, 0, stream>>>(x, Wt, h1);
    k_gather1   <<<6250, 256, 0, stream>>>(offs, esrc, h1, dinv, b1, a1);

    // layer 2
    k_gemm2_mfma<<<391,  256, 0, stream>>>(a1, Wt2, h2);
    k_gather2   <<<1563, 256, 0, stream>>>(offs, esrc, h2, dinv, b2, out);
}